// Round 2
// baseline (3376.331 us; speedup 1.0000x reference)
//
#include <hip/hip_runtime.h>
#include <math.h>

#define NTOK 16384
#define DDIM 2048
#define NEXP 64
#define RRANK 128
#define CAP 640  // ceil(1.25 * 32768 / 64)

__device__ __forceinline__ void atomAddF(float* p, float v) {
  unsafeAtomicAdd(p, v);  // native global_atomic_add_f32 on gfx950
}

__device__ __forceinline__ float silu_f(float v) {
  return v / (1.f + expf(-v));
}

// ---------------- encoder GEMM: enc[m,n] = sum_k x[m,k]*We[n,k] + be[n] ----
__global__ __launch_bounds__(256) void enc_gemm_kernel(
    const float* __restrict__ x, const float* __restrict__ We,
    const float* __restrict__ be, float* __restrict__ out)
{
  __shared__ float As[8][128];
  __shared__ float Bs[8][128];
  const int tid = threadIdx.x;
  const int n0 = blockIdx.x * 128;
  const int m0 = blockIdx.y * 128;
  const int tx = tid & 15, ty = tid >> 4;
  const int lr = tid >> 1;
  const int lk = (tid & 1) * 4;

  float acc[8][8];
#pragma unroll
  for (int i = 0; i < 8; ++i)
#pragma unroll
    for (int j = 0; j < 8; ++j) acc[i][j] = 0.f;

  const float* Ap = x + (size_t)(m0 + lr) * DDIM + lk;
  const float* Bp = We + (size_t)(n0 + lr) * DDIM + lk;

  for (int kb = 0; kb < DDIM; kb += 8) {
    const float4 av = *(const float4*)(Ap + kb);
    const float4 bv = *(const float4*)(Bp + kb);
    __syncthreads();
    As[lk + 0][lr] = av.x; As[lk + 1][lr] = av.y;
    As[lk + 2][lr] = av.z; As[lk + 3][lr] = av.w;
    Bs[lk + 0][lr] = bv.x; Bs[lk + 1][lr] = bv.y;
    Bs[lk + 2][lr] = bv.z; Bs[lk + 3][lr] = bv.w;
    __syncthreads();
#pragma unroll
    for (int k = 0; k < 8; ++k) {
      const float4 a0 = *(const float4*)&As[k][ty * 4];
      const float4 a1 = *(const float4*)&As[k][64 + ty * 4];
      const float4 b0 = *(const float4*)&Bs[k][tx * 4];
      const float4 b1 = *(const float4*)&Bs[k][64 + tx * 4];
      const float ar[8] = {a0.x, a0.y, a0.z, a0.w, a1.x, a1.y, a1.z, a1.w};
      const float br[8] = {b0.x, b0.y, b0.z, b0.w, b1.x, b1.y, b1.z, b1.w};
#pragma unroll
      for (int i = 0; i < 8; ++i)
#pragma unroll
        for (int j = 0; j < 8; ++j)
          acc[i][j] = fmaf(ar[i], br[j], acc[i][j]);
    }
  }

  const float4 bias0 = *(const float4*)(be + n0 + tx * 4);
  const float4 bias1 = *(const float4*)(be + n0 + 64 + tx * 4);
#pragma unroll
  for (int i = 0; i < 8; ++i) {
    const int m = m0 + ((i < 4) ? (ty * 4 + i) : (64 + ty * 4 + (i - 4)));
    float* op = out + (size_t)m * DDIM + n0;
    float4 c0, c1;
    c0.x = acc[i][0] + bias0.x; c0.y = acc[i][1] + bias0.y;
    c0.z = acc[i][2] + bias0.z; c0.w = acc[i][3] + bias0.w;
    c1.x = acc[i][4] + bias1.x; c1.y = acc[i][5] + bias1.y;
    c1.z = acc[i][6] + bias1.z; c1.w = acc[i][7] + bias1.w;
    *(float4*)(op + tx * 4) = c0;
    *(float4*)(op + 64 + tx * 4) = c1;
  }
}

// ---------------- G = We^T @ Wg^T  (fp64), G[d][e] ------------------------
__global__ __launch_bounds__(256) void gmat_kernel(
    const float* __restrict__ We, const float* __restrict__ Wg,
    double* __restrict__ G)
{
  __shared__ float As[64][68];  // [o][d]
  __shared__ float Bs[64][68];  // [o][e]
  const int tid = threadIdx.x;
  const int d0 = blockIdx.x * 64;
  const int tx = tid & 15, ty = tid >> 4;
  const int row = tid >> 2, p = (tid & 3) * 16;

  double acc[4][4];
#pragma unroll
  for (int j = 0; j < 4; ++j)
#pragma unroll
    for (int i = 0; i < 4; ++i) acc[j][i] = 0.0;

  for (int o0 = 0; o0 < DDIM; o0 += 64) {
    float4 wv[4], gv[4];
#pragma unroll
    for (int q = 0; q < 4; ++q) {
      wv[q] = *(const float4*)(We + (size_t)(o0 + row) * DDIM + d0 + p + q * 4);
      gv[q] = *(const float4*)(Wg + (size_t)row * DDIM + o0 + p + q * 4);
    }
    __syncthreads();
#pragma unroll
    for (int q = 0; q < 4; ++q) {
      const int c = p + q * 4;
      As[row][c + 0] = wv[q].x; As[row][c + 1] = wv[q].y;
      As[row][c + 2] = wv[q].z; As[row][c + 3] = wv[q].w;
      Bs[c + 0][row] = gv[q].x; Bs[c + 1][row] = gv[q].y;
      Bs[c + 2][row] = gv[q].z; Bs[c + 3][row] = gv[q].w;
    }
    __syncthreads();
#pragma unroll 8
    for (int oo = 0; oo < 64; ++oo) {
      double a[4], b[4];
#pragma unroll
      for (int j = 0; j < 4; ++j) a[j] = (double)As[oo][ty * 4 + j];
#pragma unroll
      for (int i = 0; i < 4; ++i) b[i] = (double)Bs[oo][tx * 4 + i];
#pragma unroll
      for (int j = 0; j < 4; ++j)
#pragma unroll
        for (int i = 0; i < 4; ++i)
          acc[j][i] = fma(a[j], b[i], acc[j][i]);
    }
  }
#pragma unroll
  for (int j = 0; j < 4; ++j)
#pragma unroll
    for (int i = 0; i < 4; ++i)
      G[(size_t)(d0 + ty * 4 + j) * NEXP + tx * 4 + i] = acc[j][i];
}

// ---------------- c[e] = be . Wg[e]  (fp64) --------------------------------
__global__ __launch_bounds__(256) void bias_c_kernel(
    const float* __restrict__ be, const float* __restrict__ Wg,
    double* __restrict__ c64)
{
  const int e = blockIdx.x;
  const int tid = threadIdx.x;
  double s = 0.0;
  for (int o = tid; o < DDIM; o += 256)
    s += (double)be[o] * (double)Wg[(size_t)e * DDIM + o];
  __shared__ double red[256];
  red[tid] = s;
  __syncthreads();
  for (int st = 128; st > 0; st >>= 1) {
    if (tid < st) red[tid] += red[tid + st];
    __syncthreads();
  }
  if (tid == 0) c64[e] = red[0];
}

// ---------------- logits = x@G + c (fp64), fused top-2 + softmax -----------
__global__ __launch_bounds__(256) void logits_kernel(
    const float* __restrict__ x, const double* __restrict__ G,
    const double* __restrict__ c64,
    int* __restrict__ topk, float* __restrict__ wkf)
{
  __shared__ float Xs[64][68];    // [d][tok]
  __shared__ double Gs[64][65];   // [d][e], reused as logits[tok][e]
  const int tid = threadIdx.x;
  const int t0 = blockIdx.x * 64;
  const int tx = tid & 15, ty = tid >> 4;
  const int xrow = tid >> 2, xp = (tid & 3) * 16;
  const int gp = tid & 3;

  double acc[4][4];
#pragma unroll
  for (int j = 0; j < 4; ++j)
#pragma unroll
    for (int i = 0; i < 4; ++i) acc[j][i] = 0.0;

  for (int d0 = 0; d0 < DDIM; d0 += 64) {
    float4 xv[4];
#pragma unroll
    for (int q = 0; q < 4; ++q)
      xv[q] = *(const float4*)(x + (size_t)(t0 + xrow) * DDIM + d0 + xp + q * 4);
    double2 gv[8];
#pragma unroll
    for (int q = 0; q < 8; ++q)
      gv[q] = *(const double2*)(G + (size_t)(d0 + xrow) * NEXP + gp * 16 + q * 2);
    __syncthreads();
#pragma unroll
    for (int q = 0; q < 4; ++q) {
      const int c = xp + q * 4;
      Xs[c + 0][xrow] = xv[q].x; Xs[c + 1][xrow] = xv[q].y;
      Xs[c + 2][xrow] = xv[q].z; Xs[c + 3][xrow] = xv[q].w;
    }
#pragma unroll
    for (int q = 0; q < 8; ++q) {
      Gs[xrow][gp * 16 + q * 2 + 0] = gv[q].x;
      Gs[xrow][gp * 16 + q * 2 + 1] = gv[q].y;
    }
    __syncthreads();
#pragma unroll 4
    for (int kk = 0; kk < 64; ++kk) {
      double xr[4], gr[4];
#pragma unroll
      for (int j = 0; j < 4; ++j) xr[j] = (double)Xs[kk][ty * 4 + j];
#pragma unroll
      for (int i = 0; i < 4; ++i) gr[i] = Gs[kk][tx * 4 + i];
#pragma unroll
      for (int j = 0; j < 4; ++j)
#pragma unroll
        for (int i = 0; i < 4; ++i)
          acc[j][i] = fma(xr[j], gr[i], acc[j][i]);
    }
  }

  double cadd[4];
#pragma unroll
  for (int i = 0; i < 4; ++i) cadd[i] = c64[tx * 4 + i];
  __syncthreads();
#pragma unroll
  for (int j = 0; j < 4; ++j)
#pragma unroll
    for (int i = 0; i < 4; ++i)
      Gs[ty * 4 + j][tx * 4 + i] = acc[j][i] + cadd[i];
  __syncthreads();

  if (tid < 64) {
    double v1 = -1e300, v2 = -1e300;
    int i1 = 0, i2 = 0;
    for (int e = 0; e < NEXP; ++e) {
      const double v = Gs[tid][e];
      if (v > v1) { v2 = v1; i2 = i1; v1 = v; i1 = e; }
      else if (v > v2) { v2 = v; i2 = e; }
    }
    const double e2 = exp(v2 - v1);
    const double s = 1.0 + e2 + 1e-12;
    const int g = t0 + tid;
    topk[2 * g] = i1; topk[2 * g + 1] = i2;
    wkf[2 * g] = (float)(1.0 / s);
    wkf[2 * g + 1] = (float)(e2 / s);
  }
}

// ------- deterministic capacity routing: rank in token order, drop >= CAP --
__global__ __launch_bounds__(256) void route_kernel(
    const int* __restrict__ topk, const float* __restrict__ wkf,
    int* __restrict__ slots /* [NEXP][CAP] */, int* __restrict__ counts_eff)
{
  const int e = blockIdx.x;
  const int tid = threadIdx.x;
  const int lane = tid & 63, wave = tid >> 6;
  __shared__ int wcnt[4];
  __shared__ int sbase;
  if (tid == 0) sbase = 0;
  __syncthreads();

  for (int c0 = 0; c0 < NTOK * 2; c0 += 256) {
    const int a = c0 + tid;
    const bool match = (topk[a] == e) && (wkf[a] > 1e-12f);
    const unsigned long long bal = __ballot(match);
    if (lane == 0) wcnt[wave] = __popcll(bal);
    __syncthreads();
    int base = sbase;
    for (int w = 0; w < 4; ++w)
      if (w < wave) base += wcnt[w];
    const int rank = base + (int)__popcll(bal & ((1ull << lane) - 1ull));
    if (match && rank < CAP) slots[e * CAP + rank] = a;
    __syncthreads();
    if (tid == 0) sbase += wcnt[0] + wcnt[1] + wcnt[2] + wcnt[3];
  }
  __syncthreads();
  if (tid == 0) counts_eff[e] = (sbase < CAP) ? sbase : CAP;
}

// ---------------- expert pass 1: H[slot] = silu(U_e @ enc[tok]) ------------
__global__ __launch_bounds__(256) void expert_h_kernel(
    const float* __restrict__ enc, const float* __restrict__ U,
    const int* __restrict__ counts_eff, const int* __restrict__ slots,
    float* __restrict__ Hbuf)
{
  const int e = blockIdx.y;
  const int cnt = counts_eff[e];
  const int t0 = blockIdx.x * 64;
  if (t0 >= cnt) return;
  const int tid = threadIdx.x;
  const int tx = tid & 15, ty = tid >> 4;

  __shared__ int toks[64];
  __shared__ float Xs[32][68];   // [k][token]
  __shared__ float Us[32][132];  // [k][r]

  if (tid < 64) {
    const int i = t0 + tid;
    toks[tid] = (i < cnt) ? (slots[e * CAP + i] >> 1) : 0;
  }
  __syncthreads();

  const int xrow = tid >> 2, xc0 = (tid & 3) * 8;
  const int ur = tid >> 1, uc0 = (tid & 1) * 16;
  const float* Xp = enc + (size_t)toks[xrow] * DDIM + xc0;
  const float* Up = U + (size_t)e * ((size_t)RRANK * DDIM) + (size_t)ur * DDIM + uc0;

  float h[4][8];
#pragma unroll
  for (int j = 0; j < 4; ++j)
#pragma unroll
    for (int i = 0; i < 8; ++i) h[j][i] = 0.f;

  for (int kb = 0; kb < DDIM; kb += 32) {
    const float4 xv0 = *(const float4*)(Xp + kb);
    const float4 xv1 = *(const float4*)(Xp + kb + 4);
    const float4 u0 = *(const float4*)(Up + kb);
    const float4 u1 = *(const float4*)(Up + kb + 4);
    const float4 u2 = *(const float4*)(Up + kb + 8);
    const float4 u3 = *(const float4*)(Up + kb + 12);
    __syncthreads();
    Xs[xc0 + 0][xrow] = xv0.x; Xs[xc0 + 1][xrow] = xv0.y;
    Xs[xc0 + 2][xrow] = xv0.z; Xs[xc0 + 3][xrow] = xv0.w;
    Xs[xc0 + 4][xrow] = xv1.x; Xs[xc0 + 5][xrow] = xv1.y;
    Xs[xc0 + 6][xrow] = xv1.z; Xs[xc0 + 7][xrow] = xv1.w;
    Us[uc0 + 0][ur] = u0.x;  Us[uc0 + 1][ur] = u0.y;
    Us[uc0 + 2][ur] = u0.z;  Us[uc0 + 3][ur] = u0.w;
    Us[uc0 + 4][ur] = u1.x;  Us[uc0 + 5][ur] = u1.y;
    Us[uc0 + 6][ur] = u1.z;  Us[uc0 + 7][ur] = u1.w;
    Us[uc0 + 8][ur] = u2.x;  Us[uc0 + 9][ur] = u2.y;
    Us[uc0 + 10][ur] = u2.z; Us[uc0 + 11][ur] = u2.w;
    Us[uc0 + 12][ur] = u3.x; Us[uc0 + 13][ur] = u3.y;
    Us[uc0 + 14][ur] = u3.z; Us[uc0 + 15][ur] = u3.w;
    __syncthreads();
#pragma unroll
    for (int kk = 0; kk < 32; ++kk) {
      const float4 xv = *(const float4*)&Xs[kk][ty * 4];
      const float4 ua = *(const float4*)&Us[kk][tx * 8];
      const float4 ub = *(const float4*)&Us[kk][tx * 8 + 4];
      const float xr[4] = {xv.x, xv.y, xv.z, xv.w};
      const float ur8[8] = {ua.x, ua.y, ua.z, ua.w, ub.x, ub.y, ub.z, ub.w};
#pragma unroll
      for (int j = 0; j < 4; ++j)
#pragma unroll
        for (int i = 0; i < 8; ++i)
          h[j][i] = fmaf(xr[j], ur8[i], h[j][i]);
    }
  }

  const int base = e * CAP + t0;
#pragma unroll
  for (int j = 0; j < 4; ++j) {
    if (t0 + ty * 4 + j < cnt) {
      float4 o0, o1;
      o0.x = silu_f(h[j][0]); o0.y = silu_f(h[j][1]);
      o0.z = silu_f(h[j][2]); o0.w = silu_f(h[j][3]);
      o1.x = silu_f(h[j][4]); o1.y = silu_f(h[j][5]);
      o1.z = silu_f(h[j][6]); o1.w = silu_f(h[j][7]);
      float* hp = Hbuf + (size_t)(base + ty * 4 + j) * RRANK + tx * 8;
      *(float4*)hp = o0;
      *(float4*)(hp + 4) = o1;
    }
  }
}

// ---------------- expert pass 2: y[tok] += w * (H @ V_e^T) ------------------
__global__ __launch_bounds__(256) void expert_out_kernel(
    const float* __restrict__ Hbuf, const float* __restrict__ V,
    const float* __restrict__ gamma, const int* __restrict__ counts_eff,
    const int* __restrict__ slots, const float* __restrict__ wkf,
    float* __restrict__ y)
{
  const int e = blockIdx.y;
  const int cnt = counts_eff[e];
  const int t0 = blockIdx.x * 64;
  if (t0 >= cnt) return;
  const int tid = threadIdx.x;
  const int tx = tid & 15, ty = tid >> 4;

  __shared__ int toks[64];
  __shared__ float wts[64];
  __shared__ float Hs[128][68];  // [r][token]
  __shared__ float Vs[64][68];   // [r][n]

  if (tid < 64) {
    const int i = t0 + tid;
    if (i < cnt) {
      const int a = slots[e * CAP + i];
      toks[tid] = a >> 1;
      wts[tid] = wkf[a] * gamma[e];
    } else {
      toks[tid] = 0;
      wts[tid] = 0.f;
    }
  }

  {
    const int hrow = tid >> 2;
    const int hc0 = (tid & 3) * 32;
    int il = t0 + hrow; if (il >= cnt) il = cnt - 1;
    const float* p = Hbuf + (size_t)(e * CAP + il) * RRANK + hc0;
#pragma unroll
    for (int q = 0; q < 8; ++q) {
      const float4 v = *(const float4*)(p + q * 4);
      Hs[hc0 + q * 4 + 0][hrow] = v.x;
      Hs[hc0 + q * 4 + 1][hrow] = v.y;
      Hs[hc0 + q * 4 + 2][hrow] = v.z;
      Hs[hc0 + q * 4 + 3][hrow] = v.w;
    }
  }
  __syncthreads();

  float wrow[4]; int trow[4];
#pragma unroll
  for (int j = 0; j < 4; ++j) { wrow[j] = wts[ty * 4 + j]; trow[j] = toks[ty * 4 + j]; }

  const float* Ve = V + (size_t)e * ((size_t)DDIM * RRANK);
  const int vn = tid >> 2, vc0 = (tid & 3) * 16;

  for (int nb = 0; nb < DDIM; nb += 64) {
    float dacc[4][4];
#pragma unroll
    for (int j = 0; j < 4; ++j)
#pragma unroll
      for (int i = 0; i < 4; ++i) dacc[j][i] = 0.f;

#pragma unroll 1
    for (int kb2 = 0; kb2 < RRANK; kb2 += 64) {
      const float* p = Ve + (size_t)(nb + vn) * RRANK + kb2 + vc0;
      const float4 v0 = *(const float4*)(p);
      const float4 v1 = *(const float4*)(p + 4);
      const float4 v2 = *(const float4*)(p + 8);
      const float4 v3 = *(const float4*)(p + 12);
      __syncthreads();
      Vs[vc0 + 0][vn] = v0.x;  Vs[vc0 + 1][vn] = v0.y;
      Vs[vc0 + 2][vn] = v0.z;  Vs[vc0 + 3][vn] = v0.w;
      Vs[vc0 + 4][vn] = v1.x;  Vs[vc0 + 5][vn] = v1.y;
      Vs[vc0 + 6][vn] = v1.z;  Vs[vc0 + 7][vn] = v1.w;
      Vs[vc0 + 8][vn] = v2.x;  Vs[vc0 + 9][vn] = v2.y;
      Vs[vc0 + 10][vn] = v2.z; Vs[vc0 + 11][vn] = v2.w;
      Vs[vc0 + 12][vn] = v3.x; Vs[vc0 + 13][vn] = v3.y;
      Vs[vc0 + 14][vn] = v3.z; Vs[vc0 + 15][vn] = v3.w;
      __syncthreads();
#pragma unroll
      for (int kk = 0; kk < 64; ++kk) {
        const float4 hv = *(const float4*)&Hs[kb2 + kk][ty * 4];
        const float4 vv = *(const float4*)&Vs[kk][tx * 4];
        const float hr[4] = {hv.x, hv.y, hv.z, hv.w};
        const float vr[4] = {vv.x, vv.y, vv.z, vv.w};
#pragma unroll
        for (int j = 0; j < 4; ++j)
#pragma unroll
          for (int i = 0; i < 4; ++i)
            dacc[j][i] = fmaf(hr[j], vr[i], dacc[j][i]);
      }
    }
#pragma unroll
    for (int j = 0; j < 4; ++j) {
      const float w = wrow[j];
      if (w != 0.f) {
        float* yp = y + (size_t)trow[j] * DDIM + nb + tx * 4;
        atomAddF(yp + 0, dacc[j][0] * w);
        atomAddF(yp + 1, dacc[j][1] * w);
        atomAddF(yp + 2, dacc[j][2] * w);
        atomAddF(yp + 3, dacc[j][3] * w);
      }
    }
  }
}

extern "C" void kernel_launch(void* const* d_in, const int* in_sizes, int n_in,
                              void* d_out, int out_size, void* d_ws, size_t ws_size,
                              hipStream_t stream)
{
  const float* x     = (const float*)d_in[0];
  const float* We    = (const float*)d_in[1];
  const float* be    = (const float*)d_in[2];
  const float* Wg    = (const float*)d_in[3];
  const float* U     = (const float*)d_in[4];
  const float* V     = (const float*)d_in[5];
  const float* gamma = (const float*)d_in[6];
  float* y = (float*)d_out;

  char* ws = (char*)d_ws;
  int*    topk       = (int*)(ws + 0);          // 32768 ints
  float*  wkf        = (float*)(ws + 131072);   // 32768 floats
  int*    counts_eff = (int*)(ws + 262144);     // 64 ints
  double* c64        = (double*)(ws + 262400);  // 64 doubles
  double* G          = (double*)(ws + 262912);  // 2048*64 doubles = 1 MB
  int*    slots      = (int*)(ws + 1311488);    // 64*640 ints
  float*  Hbuf       = (float*)(ws + 1475328);  // 64*640*128 floats = 21 MB
  // total ws use ~22.4 MB

  gmat_kernel<<<dim3(32), 256, 0, stream>>>(We, Wg, G);
  bias_c_kernel<<<dim3(64), 256, 0, stream>>>(be, Wg, c64);
  logits_kernel<<<dim3(256), 256, 0, stream>>>(x, G, c64, topk, wkf);
  route_kernel<<<dim3(64), 256, 0, stream>>>(topk, wkf, slots, counts_eff);
  // enc -> d_out (y starts as enc; experts scatter-add on top)
  enc_gemm_kernel<<<dim3(16, 128), 256, 0, stream>>>(x, We, be, y);
  expert_h_kernel<<<dim3(10, 64), 256, 0, stream>>>(y, U, counts_eff, slots, Hbuf);
  expert_out_kernel<<<dim3(10, 64), 256, 0, stream>>>(Hbuf, V, gamma, counts_eff, slots, wkf, y);
}

// Round 3
// 1139.724 us; speedup vs baseline: 2.9624x; 2.9624x over previous
//
#include <hip/hip_runtime.h>
#include <math.h>

#define NTOK 16384
#define DDIM 2048
#define NEXP 64
#define RRANK 128
#define CAP 640  // ceil(1.25 * 32768 / 64)

typedef __attribute__((ext_vector_type(8))) short bf16x8;
typedef __attribute__((ext_vector_type(4))) float f32x4;
typedef __attribute__((address_space(1))) const unsigned int gu32_t;
typedef __attribute__((address_space(3))) unsigned int lu32_t;

__device__ __forceinline__ void gload16(const void* g, void* l) {
  __builtin_amdgcn_global_load_lds((gu32_t*)g, (lu32_t*)l, 16, 0, 0);
}

__device__ __forceinline__ void atomAddF(float* p, float v) {
  unsafeAtomicAdd(p, v);  // native global_atomic_add_f32 on gfx950
}

__device__ __forceinline__ float silu_f(float v) {
  return v / (1.f + expf(-v));
}

__device__ __forceinline__ unsigned short f2bf(float f) {
  unsigned int u = __float_as_uint(f);
  unsigned int r = (u + 0x7fffu + ((u >> 16) & 1u)) >> 16;
  return (unsigned short)r;
}

__device__ __forceinline__ int swz256(int d) {  // XOR-swizzle for 256B-row tiles
  return d ^ (((d >> 8) & 7) << 4);
}

// ---------------- fp32 -> bf16 bulk convert --------------------------------
__global__ __launch_bounds__(256) void cvt_bf16_kernel(
    const float* __restrict__ in, unsigned short* __restrict__ out, int n4)
{
  int i = blockIdx.x * 256 + threadIdx.x;
  const int stride = gridDim.x * 256;
  for (; i < n4; i += stride) {
    const float4 v = ((const float4*)in)[i];
    ushort4 o;
    o.x = f2bf(v.x); o.y = f2bf(v.y); o.z = f2bf(v.z); o.w = f2bf(v.w);
    ((ushort4*)out)[i] = o;
  }
}

// ---------------- encoder GEMM (bf16 MFMA): enc = x@We^T + be --------------
// A = x [M,K] fp32 (reg-stage + cvt), B = We_bf [N,K] bf16 (global_load_lds)
__global__ __launch_bounds__(256) void enc_mfma_kernel(
    const float* __restrict__ x, const unsigned short* __restrict__ Web,
    const float* __restrict__ be, float* __restrict__ out)
{
  __shared__ unsigned short At[128 * 32];
  __shared__ unsigned short Bt[128 * 32];
  const int tid = threadIdx.x;
  const int lane = tid & 63, wid = tid >> 6;
  const int wr = wid >> 1, wc = wid & 1;
  const int fr = lane & 15, fq = lane >> 4;
  const int n0 = blockIdx.x * 128, m0 = blockIdx.y * 128;

  const int arow = tid >> 1, ak0 = (tid & 1) * 16;
  const float* ap = x + (size_t)(m0 + arow) * DDIM + ak0;
  unsigned short* awp = &At[arow * 32 + ak0];

  const int doff0 = wid * 1024 + lane * 16;
  const int doff1 = doff0 + 4096;
  const unsigned short* bsrc0 = Web + (size_t)(n0 + (doff0 >> 6)) * DDIM + ((doff0 & 63) >> 1);
  const unsigned short* bsrc1 = Web + (size_t)(n0 + (doff1 >> 6)) * DDIM + ((doff1 & 63) >> 1);
  unsigned short* bdst0 = (unsigned short*)((char*)Bt + doff0);
  unsigned short* bdst1 = (unsigned short*)((char*)Bt + doff1);

  f32x4 acc[4][4];
#pragma unroll
  for (int m = 0; m < 4; ++m)
#pragma unroll
    for (int n = 0; n < 4; ++n) acc[m][n] = (f32x4){0.f, 0.f, 0.f, 0.f};

  float4 ar[4];
#pragma unroll
  for (int q = 0; q < 4; ++q) ar[q] = *(const float4*)(ap + q * 4);

  for (int kb = 0; kb < DDIM; kb += 32) {
    __syncthreads();
    union { unsigned short us[16]; uint4 q[2]; } pk;
#pragma unroll
    for (int q = 0; q < 4; ++q) {
      pk.us[q * 4 + 0] = f2bf(ar[q].x);
      pk.us[q * 4 + 1] = f2bf(ar[q].y);
      pk.us[q * 4 + 2] = f2bf(ar[q].z);
      pk.us[q * 4 + 3] = f2bf(ar[q].w);
    }
    *(uint4*)awp = pk.q[0];
    *(uint4*)(awp + 8) = pk.q[1];
    gload16(bsrc0 + kb, bdst0);
    gload16(bsrc1 + kb, bdst1);
    __syncthreads();
    if (kb + 32 < DDIM) {
#pragma unroll
      for (int q = 0; q < 4; ++q) ar[q] = *(const float4*)(ap + kb + 32 + q * 4);
    }
    bf16x8 af[4], bfr[4];
#pragma unroll
    for (int m = 0; m < 4; ++m)
      af[m] = *(const bf16x8*)&At[(wr * 64 + m * 16 + fr) * 32 + fq * 8];
#pragma unroll
    for (int n = 0; n < 4; ++n)
      bfr[n] = *(const bf16x8*)&Bt[(wc * 64 + n * 16 + fr) * 32 + fq * 8];
#pragma unroll
    for (int m = 0; m < 4; ++m)
#pragma unroll
      for (int n = 0; n < 4; ++n)
        acc[m][n] = __builtin_amdgcn_mfma_f32_16x16x32_bf16(af[m], bfr[n], acc[m][n], 0, 0, 0);
  }

  float bias[4];
#pragma unroll
  for (int n = 0; n < 4; ++n) bias[n] = be[n0 + wc * 64 + n * 16 + fr];
#pragma unroll
  for (int m = 0; m < 4; ++m) {
#pragma unroll
    for (int j = 0; j < 4; ++j) {
      const int row = m0 + wr * 64 + m * 16 + fq * 4 + j;
      float* op = out + (size_t)row * DDIM + n0 + wc * 64 + fr;
#pragma unroll
      for (int n = 0; n < 4; ++n)
        op[n * 16] = acc[m][n][j] + bias[n];
    }
  }
}

// ---------------- G = We^T @ Wg^T  (fp64), G[d][e] ------------------------
__global__ __launch_bounds__(256) void gmat_kernel(
    const float* __restrict__ We, const float* __restrict__ Wg,
    double* __restrict__ G)
{
  __shared__ float As[64][68];  // [o][d]
  __shared__ float Bs[64][68];  // [o][e]
  const int tid = threadIdx.x;
  const int d0 = blockIdx.x * 64;
  const int tx = tid & 15, ty = tid >> 4;
  const int row = tid >> 2, p = (tid & 3) * 16;

  double acc[4][4];
#pragma unroll
  for (int j = 0; j < 4; ++j)
#pragma unroll
    for (int i = 0; i < 4; ++i) acc[j][i] = 0.0;

  for (int o0 = 0; o0 < DDIM; o0 += 64) {
    float4 wv[4], gv[4];
#pragma unroll
    for (int q = 0; q < 4; ++q) {
      wv[q] = *(const float4*)(We + (size_t)(o0 + row) * DDIM + d0 + p + q * 4);
      gv[q] = *(const float4*)(Wg + (size_t)row * DDIM + o0 + p + q * 4);
    }
    __syncthreads();
#pragma unroll
    for (int q = 0; q < 4; ++q) {
      const int c = p + q * 4;
      As[row][c + 0] = wv[q].x; As[row][c + 1] = wv[q].y;
      As[row][c + 2] = wv[q].z; As[row][c + 3] = wv[q].w;
      Bs[c + 0][row] = gv[q].x; Bs[c + 1][row] = gv[q].y;
      Bs[c + 2][row] = gv[q].z; Bs[c + 3][row] = gv[q].w;
    }
    __syncthreads();
#pragma unroll 8
    for (int oo = 0; oo < 64; ++oo) {
      double a[4], b[4];
#pragma unroll
      for (int j = 0; j < 4; ++j) a[j] = (double)As[oo][ty * 4 + j];
#pragma unroll
      for (int i = 0; i < 4; ++i) b[i] = (double)Bs[oo][tx * 4 + i];
#pragma unroll
      for (int j = 0; j < 4; ++j)
#pragma unroll
        for (int i = 0; i < 4; ++i)
          acc[j][i] = fma(a[j], b[i], acc[j][i]);
    }
  }
#pragma unroll
  for (int j = 0; j < 4; ++j)
#pragma unroll
    for (int i = 0; i < 4; ++i)
      G[(size_t)(d0 + ty * 4 + j) * NEXP + tx * 4 + i] = acc[j][i];
}

// ---------------- c[e] = be . Wg[e]  (fp64) --------------------------------
__global__ __launch_bounds__(256) void bias_c_kernel(
    const float* __restrict__ be, const float* __restrict__ Wg,
    double* __restrict__ c64)
{
  const int e = blockIdx.x;
  const int tid = threadIdx.x;
  double s = 0.0;
  for (int o = tid; o < DDIM; o += 256)
    s += (double)be[o] * (double)Wg[(size_t)e * DDIM + o];
  __shared__ double red[256];
  red[tid] = s;
  __syncthreads();
  for (int st = 128; st > 0; st >>= 1) {
    if (tid < st) red[tid] += red[tid + st];
    __syncthreads();
  }
  if (tid == 0) c64[e] = red[0];
}

// ---------------- logits = x@G + c (fp64), fused top-2 + softmax -----------
__global__ __launch_bounds__(256) void logits_kernel(
    const float* __restrict__ x, const double* __restrict__ G,
    const double* __restrict__ c64,
    int* __restrict__ topk, float* __restrict__ wkf)
{
  __shared__ float Xs[64][68];    // [d][tok]
  __shared__ double Gs[64][65];   // [d][e], reused as logits[tok][e]
  const int tid = threadIdx.x;
  const int t0 = blockIdx.x * 64;
  const int tx = tid & 15, ty = tid >> 4;
  const int xrow = tid >> 2, xp = (tid & 3) * 16;
  const int gp = tid & 3;

  double acc[4][4];
#pragma unroll
  for (int j = 0; j < 4; ++j)
#pragma unroll
    for (int i = 0; i < 4; ++i) acc[j][i] = 0.0;

  for (int d0 = 0; d0 < DDIM; d0 += 64) {
    float4 xv[4];
#pragma unroll
    for (int q = 0; q < 4; ++q)
      xv[q] = *(const float4*)(x + (size_t)(t0 + xrow) * DDIM + d0 + xp + q * 4);
    double2 gv[8];
#pragma unroll
    for (int q = 0; q < 8; ++q)
      gv[q] = *(const double2*)(G + (size_t)(d0 + xrow) * NEXP + gp * 16 + q * 2);
    __syncthreads();
#pragma unroll
    for (int q = 0; q < 4; ++q) {
      const int c = xp + q * 4;
      Xs[c + 0][xrow] = xv[q].x; Xs[c + 1][xrow] = xv[q].y;
      Xs[c + 2][xrow] = xv[q].z; Xs[c + 3][xrow] = xv[q].w;
    }
#pragma unroll
    for (int q = 0; q < 8; ++q) {
      Gs[xrow][gp * 16 + q * 2 + 0] = gv[q].x;
      Gs[xrow][gp * 16 + q * 2 + 1] = gv[q].y;
    }
    __syncthreads();
#pragma unroll 4
    for (int kk = 0; kk < 64; ++kk) {
      double xr[4], gr[4];
#pragma unroll
      for (int j = 0; j < 4; ++j) xr[j] = (double)Xs[kk][ty * 4 + j];
#pragma unroll
      for (int i = 0; i < 4; ++i) gr[i] = Gs[kk][tx * 4 + i];
#pragma unroll
      for (int j = 0; j < 4; ++j)
#pragma unroll
        for (int i = 0; i < 4; ++i)
          acc[j][i] = fma(xr[j], gr[i], acc[j][i]);
    }
  }

  double cadd[4];
#pragma unroll
  for (int i = 0; i < 4; ++i) cadd[i] = c64[tx * 4 + i];
  __syncthreads();
#pragma unroll
  for (int j = 0; j < 4; ++j)
#pragma unroll
    for (int i = 0; i < 4; ++i)
      Gs[ty * 4 + j][tx * 4 + i] = acc[j][i] + cadd[i];
  __syncthreads();

  if (tid < 64) {
    double v1 = -1e300, v2 = -1e300;
    int i1 = 0, i2 = 0;
    for (int e = 0; e < NEXP; ++e) {
      const double v = Gs[tid][e];
      if (v > v1) { v2 = v1; i2 = i1; v1 = v; i1 = e; }
      else if (v > v2) { v2 = v; i2 = e; }
    }
    const double e2 = exp(v2 - v1);
    const double s = 1.0 + e2 + 1e-12;
    const int g = t0 + tid;
    topk[2 * g] = i1; topk[2 * g + 1] = i2;
    wkf[2 * g] = (float)(1.0 / s);
    wkf[2 * g + 1] = (float)(e2 / s);
  }
}

// ------- deterministic capacity routing: rank in token order, drop >= CAP --
__global__ __launch_bounds__(256) void route_kernel(
    const int* __restrict__ topk, const float* __restrict__ wkf,
    int* __restrict__ slots /* [NEXP][CAP] */, int* __restrict__ counts_eff)
{
  const int e = blockIdx.x;
  const int tid = threadIdx.x;
  const int lane = tid & 63, wave = tid >> 6;
  __shared__ int wcnt[4];
  __shared__ int sbase;
  if (tid == 0) sbase = 0;
  __syncthreads();

  for (int c0 = 0; c0 < NTOK * 2; c0 += 256) {
    const int a = c0 + tid;
    const bool match = (topk[a] == e) && (wkf[a] > 1e-12f);
    const unsigned long long bal = __ballot(match);
    if (lane == 0) wcnt[wave] = __popcll(bal);
    __syncthreads();
    int base = sbase;
    for (int w = 0; w < 4; ++w)
      if (w < wave) base += wcnt[w];
    const int rank = base + (int)__popcll(bal & ((1ull << lane) - 1ull));
    if (match && rank < CAP) slots[e * CAP + rank] = a;
    __syncthreads();
    if (tid == 0) sbase += wcnt[0] + wcnt[1] + wcnt[2] + wcnt[3];
  }
  __syncthreads();
  if (tid == 0) counts_eff[e] = (sbase < CAP) ? sbase : CAP;
}

// -------- expert pass 1 (bf16 MFMA): H[slot][r] = silu(U_e @ enc[tok]) ----
__global__ __launch_bounds__(256) void expert_h_mfma(
    const float* __restrict__ enc, const unsigned short* __restrict__ Ub,
    const int* __restrict__ counts_eff, const int* __restrict__ slots,
    unsigned short* __restrict__ Hbuf)
{
  const int e = blockIdx.y;
  const int cnt = counts_eff[e];
  const int t0 = blockIdx.x * 64;
  if (t0 >= cnt) return;
  __shared__ unsigned short At[64 * 32];   // tokens x k
  __shared__ unsigned short Bt[128 * 32];  // r x k
  __shared__ int toks[64];
  const int tid = threadIdx.x;
  const int lane = tid & 63, wid = tid >> 6;
  const int wr = wid >> 1, wc = wid & 1;
  const int fr = lane & 15, fq = lane >> 4;

  if (tid < 64) {
    const int i = t0 + tid;
    toks[tid] = (i < cnt) ? (slots[e * CAP + i] >> 1) : (slots[e * CAP] >> 1);
  }
  __syncthreads();

  const int arow = tid >> 2, ak0 = (tid & 3) * 8;
  const float* ap = enc + (size_t)toks[arow] * DDIM + ak0;
  unsigned short* awp = &At[arow * 32 + ak0];

  const int doff0 = wid * 1024 + lane * 16;
  const int doff1 = doff0 + 4096;
  const unsigned short* Ue = Ub + (size_t)e * RRANK * DDIM;
  const unsigned short* bsrc0 = Ue + (size_t)(doff0 >> 6) * DDIM + ((doff0 & 63) >> 1);
  const unsigned short* bsrc1 = Ue + (size_t)(doff1 >> 6) * DDIM + ((doff1 & 63) >> 1);
  unsigned short* bdst0 = (unsigned short*)((char*)Bt + doff0);
  unsigned short* bdst1 = (unsigned short*)((char*)Bt + doff1);

  f32x4 acc[2][4];
#pragma unroll
  for (int m = 0; m < 2; ++m)
#pragma unroll
    for (int n = 0; n < 4; ++n) acc[m][n] = (f32x4){0.f, 0.f, 0.f, 0.f};

  float4 a0 = *(const float4*)(ap), a1 = *(const float4*)(ap + 4);

  for (int kb = 0; kb < DDIM; kb += 32) {
    __syncthreads();
    union { unsigned short us[8]; uint4 q; } pk;
    pk.us[0] = f2bf(a0.x); pk.us[1] = f2bf(a0.y);
    pk.us[2] = f2bf(a0.z); pk.us[3] = f2bf(a0.w);
    pk.us[4] = f2bf(a1.x); pk.us[5] = f2bf(a1.y);
    pk.us[6] = f2bf(a1.z); pk.us[7] = f2bf(a1.w);
    *(uint4*)awp = pk.q;
    gload16(bsrc0 + kb, bdst0);
    gload16(bsrc1 + kb, bdst1);
    __syncthreads();
    if (kb + 32 < DDIM) {
      a0 = *(const float4*)(ap + kb + 32);
      a1 = *(const float4*)(ap + kb + 36);
    }
    bf16x8 af[2], bfr[4];
#pragma unroll
    for (int m = 0; m < 2; ++m)
      af[m] = *(const bf16x8*)&At[(wr * 32 + m * 16 + fr) * 32 + fq * 8];
#pragma unroll
    for (int n = 0; n < 4; ++n)
      bfr[n] = *(const bf16x8*)&Bt[(wc * 64 + n * 16 + fr) * 32 + fq * 8];
#pragma unroll
    for (int m = 0; m < 2; ++m)
#pragma unroll
      for (int n = 0; n < 4; ++n)
        acc[m][n] = __builtin_amdgcn_mfma_f32_16x16x32_bf16(af[m], bfr[n], acc[m][n], 0, 0, 0);
  }

#pragma unroll
  for (int m = 0; m < 2; ++m) {
#pragma unroll
    for (int j = 0; j < 4; ++j) {
      const int tl = wr * 32 + m * 16 + fq * 4 + j;
      if (t0 + tl < cnt) {
        unsigned short* hp = Hbuf + (size_t)(e * CAP + t0 + tl) * RRANK + wc * 64 + fr;
#pragma unroll
        for (int n = 0; n < 4; ++n)
          hp[n * 16] = f2bf(silu_f(acc[m][n][j]));
      }
    }
  }
}

// -------- expert pass 2 (bf16 MFMA): y[tok] += w * (H @ V_e^T) -------------
__global__ __launch_bounds__(256) void expert_out_mfma(
    const unsigned short* __restrict__ Hbuf, const unsigned short* __restrict__ Vb,
    const float* __restrict__ gamma, const int* __restrict__ counts_eff,
    const int* __restrict__ slots, const float* __restrict__ wkf,
    float* __restrict__ y)
{
  const int e = blockIdx.y;
  const int cnt = counts_eff[e];
  const int t0 = blockIdx.x * 64;
  if (t0 >= cnt) return;
  __shared__ unsigned short Ht[64 * 128];   // tokens x r (swizzled)
  __shared__ unsigned short Vt[128 * 128];  // d x r (swizzled)
  __shared__ int toks[64];
  __shared__ float wts[64];
  const int tid = threadIdx.x;
  const int lane = tid & 63, wid = tid >> 6;
  const int wr = wid >> 1, wc = wid & 1;
  const int fr = lane & 15, fq = lane >> 4;

  if (tid < 64) {
    const int i = t0 + tid;
    if (i < cnt) {
      const int a = slots[e * CAP + i];
      toks[tid] = a >> 1;
      wts[tid] = wkf[a] * gamma[e];
    } else { toks[tid] = 0; wts[tid] = 0.f; }
  }

  // stage Ht: contiguous 16 KB, linear dest + swizzled source
  const unsigned short* hsrc = Hbuf + (size_t)(e * CAP + t0) * RRANK;
  const int hd = wid * 1024 + lane * 16;
#pragma unroll
  for (int is = 0; is < 4; ++is) {
    const int d = is * 4096 + hd;
    gload16(hsrc + (swz256(d) >> 1), (char*)Ht + d);
  }

  const unsigned short* vsrc0 = Vb + (size_t)e * DDIM * RRANK;

  bf16x8 af[2][4];
  float wv[2][4];
  int tk[2][4];

  for (int nb = 0; nb < 16; ++nb) {
    __syncthreads();
    const unsigned short* vsrc = vsrc0 + (size_t)nb * 128 * RRANK;
#pragma unroll
    for (int is = 0; is < 8; ++is) {
      const int d = is * 4096 + hd;
      gload16(vsrc + (swz256(d) >> 1), (char*)Vt + d);
    }
    __syncthreads();
    if (nb == 0) {
#pragma unroll
      for (int m = 0; m < 2; ++m) {
        const int row = wr * 32 + m * 16 + fr;
#pragma unroll
        for (int kk = 0; kk < 4; ++kk) {
          const int b = (row * 256 + kk * 64 + fq * 16) ^ ((row & 7) << 4);
          af[m][kk] = *(const bf16x8*)((const char*)Ht + b);
        }
#pragma unroll
        for (int j = 0; j < 4; ++j) {
          const int tl = wr * 32 + m * 16 + fq * 4 + j;
          wv[m][j] = wts[tl];
          tk[m][j] = toks[tl];
        }
      }
    }

    f32x4 acc[2][4];
#pragma unroll
    for (int m = 0; m < 2; ++m)
#pragma unroll
      for (int n = 0; n < 4; ++n) acc[m][n] = (f32x4){0.f, 0.f, 0.f, 0.f};

#pragma unroll
    for (int n = 0; n < 4; ++n) {
      const int drow = wc * 64 + n * 16 + fr;
#pragma unroll
      for (int kk = 0; kk < 4; ++kk) {
        const int b = (drow * 256 + kk * 64 + fq * 16) ^ ((drow & 7) << 4);
        const bf16x8 bfr = *(const bf16x8*)((const char*)Vt + b);
#pragma unroll
        for (int m = 0; m < 2; ++m)
          acc[m][n] = __builtin_amdgcn_mfma_f32_16x16x32_bf16(af[m][kk], bfr, acc[m][n], 0, 0, 0);
      }
    }

#pragma unroll
    for (int m = 0; m < 2; ++m) {
#pragma unroll
      for (int j = 0; j < 4; ++j) {
        const float w = wv[m][j];
        if (w != 0.f) {
          float* yp = y + (size_t)tk[m][j] * DDIM + nb * 128 + wc * 64 + fr;
#pragma unroll
          for (int n = 0; n < 4; ++n)
            atomAddF(yp + n * 16, acc[m][n][j] * w);
        }
      }
    }
  }
}

extern "C" void kernel_launch(void* const* d_in, const int* in_sizes, int n_in,
                              void* d_out, int out_size, void* d_ws, size_t ws_size,
                              hipStream_t stream)
{
  const float* x     = (const float*)d_in[0];
  const float* We    = (const float*)d_in[1];
  const float* be    = (const float*)d_in[2];
  const float* Wg    = (const float*)d_in[3];
  const float* U     = (const float*)d_in[4];
  const float* V     = (const float*)d_in[5];
  const float* gamma = (const float*)d_in[6];
  float* y = (float*)d_out;

  char* ws = (char*)d_ws;
  int*            topk       = (int*)(ws + 0);                  // 131072 B
  float*          wkf        = (float*)(ws + 131072);           // 131072 B
  int*            counts_eff = (int*)(ws + 262144);             // 256 B
  double*         c64        = (double*)(ws + 262400);          // 512 B
  double*         G          = (double*)(ws + 262912);          // 1 MB
  int*            slots      = (int*)(ws + 1311488);            // 160 KB
  unsigned short* We_bf      = (unsigned short*)(ws + 1475328); // 8.39 MB
  unsigned short* U_bf       = (unsigned short*)(ws + 9863936); // 33.6 MB
  unsigned short* V_bf       = (unsigned short*)(ws + 43418368);// 33.6 MB
  unsigned short* Hbuf       = (unsigned short*)(ws + 76972800);// 10.5 MB
  // total ws use ~87.5 MB

  cvt_bf16_kernel<<<dim3(2048), 256, 0, stream>>>(We, We_bf, DDIM * DDIM / 4);
  cvt_bf16_kernel<<<dim3(2048), 256, 0, stream>>>(U, U_bf, NEXP * RRANK * DDIM / 4);
  cvt_bf16_kernel<<<dim3(2048), 256, 0, stream>>>(V, V_bf, NEXP * DDIM * RRANK / 4);

  gmat_kernel<<<dim3(32), 256, 0, stream>>>(We, Wg, G);
  bias_c_kernel<<<dim3(64), 256, 0, stream>>>(be, Wg, c64);
  logits_kernel<<<dim3(256), 256, 0, stream>>>(x, G, c64, topk, wkf);
  route_kernel<<<dim3(64), 256, 0, stream>>>(topk, wkf, slots, counts_eff);

  enc_mfma_kernel<<<dim3(16, 128), 256, 0, stream>>>(x, We_bf, be, y);
  expert_h_mfma<<<dim3(10, 64), 256, 0, stream>>>(y, U_bf, counts_eff, slots, Hbuf);
  expert_out_mfma<<<dim3(10, 64), 256, 0, stream>>>(Hbuf, V_bf, gamma, counts_eff, slots, wkf, y);
}

// Round 4
// 1045.624 us; speedup vs baseline: 3.2290x; 1.0900x over previous
//
#include <hip/hip_runtime.h>
#include <math.h>

#define NTOK 16384
#define DDIM 2048
#define NEXP 64
#define RRANK 128
#define CAP 640  // ceil(1.25 * 32768 / 64)

typedef __attribute__((ext_vector_type(8))) short bf16x8;
typedef __attribute__((ext_vector_type(4))) float f32x4;
typedef __attribute__((address_space(1))) const unsigned int gu32_t;
typedef __attribute__((address_space(3))) unsigned int lu32_t;

__device__ __forceinline__ void gload16(const void* g, void* l) {
  __builtin_amdgcn_global_load_lds((gu32_t*)g, (lu32_t*)l, 16, 0, 0);
}

__device__ __forceinline__ void atomAddF(float* p, float v) {
  unsafeAtomicAdd(p, v);  // native global_atomic_add_f32 on gfx950
}

__device__ __forceinline__ float silu_f(float v) {
  return v / (1.f + expf(-v));
}

__device__ __forceinline__ unsigned short f2bf(float f) {
  unsigned int u = __float_as_uint(f);
  unsigned int r = (u + 0x7fffu + ((u >> 16) & 1u)) >> 16;
  return (unsigned short)r;
}

__device__ __forceinline__ int swz256(int d) {  // XOR-swizzle for 256B-row tiles
  return d ^ (((d >> 8) & 7) << 4);
}

// ---------------- fp32 -> bf16 bulk convert --------------------------------
__global__ __launch_bounds__(256) void cvt_bf16_kernel(
    const float* __restrict__ in, unsigned short* __restrict__ out, int n4)
{
  int i = blockIdx.x * 256 + threadIdx.x;
  const int stride = gridDim.x * 256;
  for (; i < n4; i += stride) {
    const float4 v = ((const float4*)in)[i];
    ushort4 o;
    o.x = f2bf(v.x); o.y = f2bf(v.y); o.z = f2bf(v.z); o.w = f2bf(v.w);
    ((ushort4*)out)[i] = o;
  }
}

// ---------------- encoder GEMM (bf16 MFMA): enc = x@We^T + be --------------
// both operands bf16 via global_load_lds; XCD-swizzled 1D grid (2048 wgs)
__global__ __launch_bounds__(256) void enc_mfma2(
    const unsigned short* __restrict__ xb, const unsigned short* __restrict__ Web,
    const float* __restrict__ be, float* __restrict__ out)
{
  __shared__ unsigned short At[128 * 32];
  __shared__ unsigned short Bt[128 * 32];
  const int tid = threadIdx.x;
  const int lane = tid & 63, wid = tid >> 6;
  const int wr = wid >> 1, wc = wid & 1;
  const int fr = lane & 15, fq = lane >> 4;
  const int bid = blockIdx.x;
  const int wg = (bid & 7) * 256 + (bid >> 3);  // bijective XCD swizzle
  const int n0 = (wg & 15) * 128, m0 = (wg >> 4) * 128;

  const int doff0 = wid * 1024 + lane * 16;
  const int doff1 = doff0 + 4096;
  const unsigned short* as0 = xb + (size_t)(m0 + (doff0 >> 6)) * DDIM + ((doff0 & 63) >> 1);
  const unsigned short* as1 = xb + (size_t)(m0 + (doff1 >> 6)) * DDIM + ((doff1 & 63) >> 1);
  const unsigned short* bs0 = Web + (size_t)(n0 + (doff0 >> 6)) * DDIM + ((doff0 & 63) >> 1);
  const unsigned short* bs1 = Web + (size_t)(n0 + (doff1 >> 6)) * DDIM + ((doff1 & 63) >> 1);
  char* ad0 = (char*)At + doff0; char* ad1 = (char*)At + doff1;
  char* bd0 = (char*)Bt + doff0; char* bd1 = (char*)Bt + doff1;

  f32x4 acc[4][4];
#pragma unroll
  for (int m = 0; m < 4; ++m)
#pragma unroll
    for (int n = 0; n < 4; ++n) acc[m][n] = (f32x4){0.f, 0.f, 0.f, 0.f};

  for (int kb = 0; kb < DDIM; kb += 32) {
    __syncthreads();
    gload16(as0 + kb, ad0);
    gload16(as1 + kb, ad1);
    gload16(bs0 + kb, bd0);
    gload16(bs1 + kb, bd1);
    __syncthreads();
    bf16x8 af[4], bfr[4];
#pragma unroll
    for (int m = 0; m < 4; ++m)
      af[m] = *(const bf16x8*)&At[(wr * 64 + m * 16 + fr) * 32 + fq * 8];
#pragma unroll
    for (int n = 0; n < 4; ++n)
      bfr[n] = *(const bf16x8*)&Bt[(wc * 64 + n * 16 + fr) * 32 + fq * 8];
#pragma unroll
    for (int m = 0; m < 4; ++m)
#pragma unroll
      for (int n = 0; n < 4; ++n)
        acc[m][n] = __builtin_amdgcn_mfma_f32_16x16x32_bf16(af[m], bfr[n], acc[m][n], 0, 0, 0);
  }

  float bias[4];
#pragma unroll
  for (int n = 0; n < 4; ++n) bias[n] = be[n0 + wc * 64 + n * 16 + fr];
#pragma unroll
  for (int m = 0; m < 4; ++m) {
#pragma unroll
    for (int j = 0; j < 4; ++j) {
      const int row = m0 + wr * 64 + m * 16 + fq * 4 + j;
      float* op = out + (size_t)row * DDIM + n0 + wc * 64 + fr;
#pragma unroll
      for (int n = 0; n < 4; ++n)
        op[n * 16] = acc[m][n][j] + bias[n];
    }
  }
}

// ------- G (fp64): Gt[e][d] = sum_o We[o][d]*Wg[e][o]; also G_bf[e][d] -----
__global__ __launch_bounds__(256) void gmat_kernel(
    const float* __restrict__ We, const float* __restrict__ Wg,
    double* __restrict__ Gt, unsigned short* __restrict__ Gbf)
{
  __shared__ float As[64][68];  // [o][d]
  __shared__ float Bs[64][68];  // [o][e]
  const int tid = threadIdx.x;
  const int d0 = blockIdx.x * 64;
  const int tx = tid & 15, ty = tid >> 4;
  const int row = tid >> 2, p = (tid & 3) * 16;

  double acc[4][4];
#pragma unroll
  for (int j = 0; j < 4; ++j)
#pragma unroll
    for (int i = 0; i < 4; ++i) acc[j][i] = 0.0;

  for (int o0 = 0; o0 < DDIM; o0 += 64) {
    float4 wv[4], gv[4];
#pragma unroll
    for (int q = 0; q < 4; ++q) {
      wv[q] = *(const float4*)(We + (size_t)(o0 + row) * DDIM + d0 + p + q * 4);
      gv[q] = *(const float4*)(Wg + (size_t)row * DDIM + o0 + p + q * 4);
    }
    __syncthreads();
#pragma unroll
    for (int q = 0; q < 4; ++q) {
      const int c = p + q * 4;
      As[row][c + 0] = wv[q].x; As[row][c + 1] = wv[q].y;
      As[row][c + 2] = wv[q].z; As[row][c + 3] = wv[q].w;
      Bs[c + 0][row] = gv[q].x; Bs[c + 1][row] = gv[q].y;
      Bs[c + 2][row] = gv[q].z; Bs[c + 3][row] = gv[q].w;
    }
    __syncthreads();
#pragma unroll 8
    for (int oo = 0; oo < 64; ++oo) {
      double a[4], b[4];
#pragma unroll
      for (int j = 0; j < 4; ++j) a[j] = (double)As[oo][ty * 4 + j];
#pragma unroll
      for (int i = 0; i < 4; ++i) b[i] = (double)Bs[oo][tx * 4 + i];
#pragma unroll
      for (int j = 0; j < 4; ++j)
#pragma unroll
        for (int i = 0; i < 4; ++i)
          acc[j][i] = fma(a[j], b[i], acc[j][i]);
    }
  }
#pragma unroll
  for (int j = 0; j < 4; ++j)
#pragma unroll
    for (int i = 0; i < 4; ++i) {
      const int d = d0 + ty * 4 + j, e = tx * 4 + i;
      Gt[(size_t)e * DDIM + d] = acc[j][i];
      Gbf[(size_t)e * DDIM + d] = f2bf((float)acc[j][i]);
    }
}

// ---------------- c[e] = be . Wg[e]  (fp64) --------------------------------
__global__ __launch_bounds__(256) void bias_c_kernel(
    const float* __restrict__ be, const float* __restrict__ Wg,
    double* __restrict__ c64)
{
  const int e = blockIdx.x;
  const int tid = threadIdx.x;
  double s = 0.0;
  for (int o = tid; o < DDIM; o += 256)
    s += (double)be[o] * (double)Wg[(size_t)e * DDIM + o];
  __shared__ double red[256];
  red[tid] = s;
  __syncthreads();
  for (int st = 128; st > 0; st >>= 1) {
    if (tid < st) red[tid] += red[tid + st];
    __syncthreads();
  }
  if (tid == 0) c64[e] = red[0];
}

// ---- approx logits (bf16 MFMA) + fused per-token top-8 candidates ---------
__global__ __launch_bounds__(256) void logits_topc_kernel(
    const unsigned short* __restrict__ xb, const unsigned short* __restrict__ Gbf,
    const double* __restrict__ c64, int* __restrict__ cand8)
{
  __shared__ unsigned short At[128 * 32];  // 8 KB: tokens x k
  __shared__ unsigned short Bt[64 * 32];   // 4 KB: experts x k
  __shared__ float Ls[128][64];            // 32 KB logits
  const int tid = threadIdx.x;
  const int lane = tid & 63, wid = tid >> 6;
  const int fr = lane & 15, fq = lane >> 4;
  const int t0 = blockIdx.x * 128;

  const int doff0 = wid * 1024 + lane * 16;  // == tid*16
  const int doff1 = doff0 + 4096;
  const unsigned short* as0 = xb + (size_t)(t0 + (doff0 >> 6)) * DDIM + ((doff0 & 63) >> 1);
  const unsigned short* as1 = xb + (size_t)(t0 + (doff1 >> 6)) * DDIM + ((doff1 & 63) >> 1);
  const unsigned short* bs0 = Gbf + (size_t)(doff0 >> 6) * DDIM + ((doff0 & 63) >> 1);
  char* ad0 = (char*)At + doff0; char* ad1 = (char*)At + doff1;
  char* bd0 = (char*)Bt + doff0;

  f32x4 acc[2][4];
#pragma unroll
  for (int m = 0; m < 2; ++m)
#pragma unroll
    for (int n = 0; n < 4; ++n) acc[m][n] = (f32x4){0.f, 0.f, 0.f, 0.f};

  for (int kb = 0; kb < DDIM; kb += 32) {
    __syncthreads();
    gload16(as0 + kb, ad0);
    gload16(as1 + kb, ad1);
    gload16(bs0 + kb, bd0);
    __syncthreads();
    bf16x8 af[2], bfr[4];
#pragma unroll
    for (int m = 0; m < 2; ++m)
      af[m] = *(const bf16x8*)&At[(wid * 32 + m * 16 + fr) * 32 + fq * 8];
#pragma unroll
    for (int n = 0; n < 4; ++n)
      bfr[n] = *(const bf16x8*)&Bt[(n * 16 + fr) * 32 + fq * 8];
#pragma unroll
    for (int m = 0; m < 2; ++m)
#pragma unroll
      for (int n = 0; n < 4; ++n)
        acc[m][n] = __builtin_amdgcn_mfma_f32_16x16x32_bf16(af[m], bfr[n], acc[m][n], 0, 0, 0);
  }

#pragma unroll
  for (int m = 0; m < 2; ++m)
#pragma unroll
    for (int j = 0; j < 4; ++j) {
      const int row = wid * 32 + m * 16 + fq * 4 + j;
#pragma unroll
      for (int n = 0; n < 4; ++n)
        Ls[row][n * 16 + fr] = acc[m][n][j];
    }
  __syncthreads();

  if (tid < 128) {
    float v8[8];
    int i8[8];
#pragma unroll
    for (int c = 0; c < 8; ++c) { v8[c] = -INFINITY; i8[c] = 0; }
    for (int e = 0; e < NEXP; ++e) {
      const float v = Ls[tid][e] + (float)c64[e];
      if (v > v8[7]) {
        int p = 7;
        while (p > 0 && v > v8[p - 1]) { v8[p] = v8[p - 1]; i8[p] = i8[p - 1]; --p; }
        v8[p] = v; i8[p] = e;
      }
    }
    int* cp = cand8 + (size_t)(t0 + tid) * 8;
#pragma unroll
    for (int c = 0; c < 8; ++c) cp[c] = i8[c];
  }
}

// ---- exact fp64 refine of 8 candidates: top-2 + softmax -------------------
__global__ __launch_bounds__(256) void refine_kernel(
    const float* __restrict__ x, const double* __restrict__ Gt,
    const double* __restrict__ c64, const int* __restrict__ cand8,
    int* __restrict__ topk, float* __restrict__ wkf)
{
  const int t = blockIdx.x;
  const int tid = threadIdx.x;
  const int lane = tid & 63, w = tid >> 6;
  __shared__ float xs[DDIM];
  __shared__ double red[8][4];

  ((float4*)xs)[tid] = ((const float4*)(x + (size_t)t * DDIM))[tid];
  ((float4*)xs)[tid + 256] = ((const float4*)(x + (size_t)t * DDIM))[tid + 256];
  __syncthreads();

  int myc[8];
#pragma unroll
  for (int c = 0; c < 8; ++c) myc[c] = cand8[(size_t)t * 8 + c];

#pragma unroll
  for (int c = 0; c < 8; ++c) {
    const double* g = Gt + (size_t)myc[c] * DDIM;
    double s = 0.0;
#pragma unroll
    for (int q = 0; q < 8; ++q) {
      const int d = q * 256 + tid;
      s += (double)xs[d] * g[d];
    }
#pragma unroll
    for (int off = 32; off > 0; off >>= 1) s += __shfl_down(s, off);
    if (lane == 0) red[c][w] = s;
  }
  __syncthreads();

  if (tid == 0) {
    double v1 = -1e300, v2 = -1e300;
    int i1 = 0, i2 = 0;
#pragma unroll
    for (int c = 0; c < 8; ++c) {
      const double v = red[c][0] + red[c][1] + red[c][2] + red[c][3] + c64[myc[c]];
      if (v > v1) { v2 = v1; i2 = i1; v1 = v; i1 = myc[c]; }
      else if (v > v2) { v2 = v; i2 = myc[c]; }
    }
    const double e2 = exp(v2 - v1);
    const double s = 1.0 + e2 + 1e-12;
    topk[2 * t] = i1; topk[2 * t + 1] = i2;
    wkf[2 * t] = (float)(1.0 / s);
    wkf[2 * t + 1] = (float)(e2 / s);
  }
}

// ------- deterministic capacity routing: rank in token order, drop >= CAP --
__global__ __launch_bounds__(256) void route_kernel(
    const int* __restrict__ topk, const float* __restrict__ wkf,
    int* __restrict__ slots /* [NEXP][CAP] */, int* __restrict__ counts_eff)
{
  const int e = blockIdx.x;
  const int tid = threadIdx.x;
  const int lane = tid & 63, wave = tid >> 6;
  __shared__ int wcnt[4];
  __shared__ int sbase;
  if (tid == 0) sbase = 0;
  __syncthreads();

  for (int c0 = 0; c0 < NTOK * 2; c0 += 256) {
    const int a = c0 + tid;
    const bool match = (topk[a] == e) && (wkf[a] > 1e-12f);
    const unsigned long long bal = __ballot(match);
    if (lane == 0) wcnt[wave] = __popcll(bal);
    __syncthreads();
    int base = sbase;
    for (int w = 0; w < 4; ++w)
      if (w < wave) base += wcnt[w];
    const int rank = base + (int)__popcll(bal & ((1ull << lane) - 1ull));
    if (match && rank < CAP) slots[e * CAP + rank] = a;
    __syncthreads();
    if (tid == 0) sbase += wcnt[0] + wcnt[1] + wcnt[2] + wcnt[3];
  }
  __syncthreads();
  if (tid == 0) counts_eff[e] = (sbase < CAP) ? sbase : CAP;
}

// -------- expert pass 1 (bf16 MFMA): H[slot][r] = silu(U_e @ enc[tok]) ----
__global__ __launch_bounds__(256) void expert_h_mfma(
    const float* __restrict__ enc, const unsigned short* __restrict__ Ub,
    const int* __restrict__ counts_eff, const int* __restrict__ slots,
    unsigned short* __restrict__ Hbuf)
{
  const int lin = blockIdx.x;                   // 640 wgs
  const int wg = (lin & 7) * 80 + (lin >> 3);   // XCD swizzle: expert locality
  const int e = wg / 10;
  const int t0 = (wg % 10) * 64;
  const int cnt = counts_eff[e];
  if (t0 >= cnt) return;
  __shared__ unsigned short At[64 * 32];   // tokens x k
  __shared__ unsigned short Bt[128 * 32];  // r x k
  __shared__ int toks[64];
  const int tid = threadIdx.x;
  const int lane = tid & 63, wid = tid >> 6;
  const int wr = wid >> 1, wc = wid & 1;
  const int fr = lane & 15, fq = lane >> 4;

  if (tid < 64) {
    const int i = t0 + tid;
    toks[tid] = (i < cnt) ? (slots[e * CAP + i] >> 1) : (slots[e * CAP] >> 1);
  }
  __syncthreads();

  const int arow = tid >> 2, ak0 = (tid & 3) * 8;
  const float* ap = enc + (size_t)toks[arow] * DDIM + ak0;
  unsigned short* awp = &At[arow * 32 + ak0];

  const int doff0 = wid * 1024 + lane * 16;
  const int doff1 = doff0 + 4096;
  const unsigned short* Ue = Ub + (size_t)e * RRANK * DDIM;
  const unsigned short* bsrc0 = Ue + (size_t)(doff0 >> 6) * DDIM + ((doff0 & 63) >> 1);
  const unsigned short* bsrc1 = Ue + (size_t)(doff1 >> 6) * DDIM + ((doff1 & 63) >> 1);
  unsigned short* bdst0 = (unsigned short*)((char*)Bt + doff0);
  unsigned short* bdst1 = (unsigned short*)((char*)Bt + doff1);

  f32x4 acc[2][4];
#pragma unroll
  for (int m = 0; m < 2; ++m)
#pragma unroll
    for (int n = 0; n < 4; ++n) acc[m][n] = (f32x4){0.f, 0.f, 0.f, 0.f};

  float4 a0 = *(const float4*)(ap), a1 = *(const float4*)(ap + 4);

  for (int kb = 0; kb < DDIM; kb += 32) {
    __syncthreads();
    union { unsigned short us[8]; uint4 q; } pk;
    pk.us[0] = f2bf(a0.x); pk.us[1] = f2bf(a0.y);
    pk.us[2] = f2bf(a0.z); pk.us[3] = f2bf(a0.w);
    pk.us[4] = f2bf(a1.x); pk.us[5] = f2bf(a1.y);
    pk.us[6] = f2bf(a1.z); pk.us[7] = f2bf(a1.w);
    *(uint4*)awp = pk.q;
    gload16(bsrc0 + kb, bdst0);
    gload16(bsrc1 + kb, bdst1);
    __syncthreads();
    if (kb + 32 < DDIM) {
      a0 = *(const float4*)(ap + kb + 32);
      a1 = *(const float4*)(ap + kb + 36);
    }
    bf16x8 af[2], bfr[4];
#pragma unroll
    for (int m = 0; m < 2; ++m)
      af[m] = *(const bf16x8*)&At[(wr * 32 + m * 16 + fr) * 32 + fq * 8];
#pragma unroll
    for (int n = 0; n < 4; ++n)
      bfr[n] = *(const bf16x8*)&Bt[(wc * 64 + n * 16 + fr) * 32 + fq * 8];
#pragma unroll
    for (int m = 0; m < 2; ++m)
#pragma unroll
      for (int n = 0; n < 4; ++n)
        acc[m][n] = __builtin_amdgcn_mfma_f32_16x16x32_bf16(af[m], bfr[n], acc[m][n], 0, 0, 0);
  }

#pragma unroll
  for (int m = 0; m < 2; ++m) {
#pragma unroll
    for (int j = 0; j < 4; ++j) {
      const int tl = wr * 32 + m * 16 + fq * 4 + j;
      if (t0 + tl < cnt) {
        unsigned short* hp = Hbuf + (size_t)(e * CAP + t0 + tl) * RRANK + wc * 64 + fr;
#pragma unroll
        for (int n = 0; n < 4; ++n)
          hp[n * 16] = f2bf(silu_f(acc[m][n][j]));
      }
    }
  }
}

// -------- expert pass 2 (bf16 MFMA): y[tok] += w * (H @ V_e^T) -------------
__global__ __launch_bounds__(256) void expert_out_mfma(
    const unsigned short* __restrict__ Hbuf, const unsigned short* __restrict__ Vb,
    const float* __restrict__ gamma, const int* __restrict__ counts_eff,
    const int* __restrict__ slots, const float* __restrict__ wkf,
    float* __restrict__ y)
{
  const int lin = blockIdx.x;                   // 640 wgs
  const int wg = (lin & 7) * 80 + (lin >> 3);   // XCD swizzle: expert locality
  const int e = wg / 10;
  const int t0 = (wg % 10) * 64;
  const int cnt = counts_eff[e];
  if (t0 >= cnt) return;
  __shared__ unsigned short Ht[64 * 128];   // tokens x r (swizzled)
  __shared__ unsigned short Vt[128 * 128];  // d x r (swizzled)
  __shared__ int toks[64];
  __shared__ float wts[64];
  const int tid = threadIdx.x;
  const int lane = tid & 63, wid = tid >> 6;
  const int wr = wid >> 1, wc = wid & 1;
  const int fr = lane & 15, fq = lane >> 4;

  if (tid < 64) {
    const int i = t0 + tid;
    if (i < cnt) {
      const int a = slots[e * CAP + i];
      toks[tid] = a >> 1;
      wts[tid] = wkf[a] * gamma[e];
    } else { toks[tid] = 0; wts[tid] = 0.f; }
  }

  // stage Ht: contiguous 16 KB, linear dest + swizzled source
  const unsigned short* hsrc = Hbuf + (size_t)(e * CAP + t0) * RRANK;
  const int hd = wid * 1024 + lane * 16;
#pragma unroll
  for (int is = 0; is < 4; ++is) {
    const int d = is * 4096 + hd;
    gload16(hsrc + (swz256(d) >> 1), (char*)Ht + d);
  }

  const unsigned short* vsrc0 = Vb + (size_t)e * DDIM * RRANK;

  bf16x8 af[2][4];
  float wv[2][4];
  int tk[2][4];

  for (int nb = 0; nb < 16; ++nb) {
    __syncthreads();
    const unsigned short* vsrc = vsrc0 + (size_t)nb * 128 * RRANK;
#pragma unroll
    for (int is = 0; is < 8; ++is) {
      const int d = is * 4096 + hd;
      gload16(vsrc + (swz256(d) >> 1), (char*)Vt + d);
    }
    __syncthreads();
    if (nb == 0) {
#pragma unroll
      for (int m = 0; m < 2; ++m) {
        const int row = wr * 32 + m * 16 + fr;
#pragma unroll
        for (int kk = 0; kk < 4; ++kk) {
          const int b = (row * 256 + kk * 64 + fq * 16) ^ ((row & 7) << 4);
          af[m][kk] = *(const bf16x8*)((const char*)Ht + b);
        }
#pragma unroll
        for (int j = 0; j < 4; ++j) {
          const int tl = wr * 32 + m * 16 + fq * 4 + j;
          wv[m][j] = wts[tl];
          tk[m][j] = toks[tl];
        }
      }
    }

    f32x4 acc[2][4];
#pragma unroll
    for (int m = 0; m < 2; ++m)
#pragma unroll
      for (int n = 0; n < 4; ++n) acc[m][n] = (f32x4){0.f, 0.f, 0.f, 0.f};

#pragma unroll
    for (int n = 0; n < 4; ++n) {
      const int drow = wc * 64 + n * 16 + fr;
#pragma unroll
      for (int kk = 0; kk < 4; ++kk) {
        const int b = (drow * 256 + kk * 64 + fq * 16) ^ ((drow & 7) << 4);
        const bf16x8 bfr = *(const bf16x8*)((const char*)Vt + b);
#pragma unroll
        for (int m = 0; m < 2; ++m)
          acc[m][n] = __builtin_amdgcn_mfma_f32_16x16x32_bf16(af[m][kk], bfr, acc[m][n], 0, 0, 0);
      }
    }

#pragma unroll
    for (int m = 0; m < 2; ++m) {
#pragma unroll
      for (int j = 0; j < 4; ++j) {
        const float w = wv[m][j];
        if (w != 0.f) {
          float* yp = y + (size_t)tk[m][j] * DDIM + nb * 128 + wc * 64 + fr;
#pragma unroll
          for (int n = 0; n < 4; ++n)
            atomAddF(yp + n * 16, acc[m][n][j] * w);
        }
      }
    }
  }
}

extern "C" void kernel_launch(void* const* d_in, const int* in_sizes, int n_in,
                              void* d_out, int out_size, void* d_ws, size_t ws_size,
                              hipStream_t stream)
{
  const float* x     = (const float*)d_in[0];
  const float* We    = (const float*)d_in[1];
  const float* be    = (const float*)d_in[2];
  const float* Wg    = (const float*)d_in[3];
  const float* U     = (const float*)d_in[4];
  const float* V     = (const float*)d_in[5];
  const float* gamma = (const float*)d_in[6];
  float* y = (float*)d_out;

  char* ws = (char*)d_ws;
  int*            topk       = (int*)(ws + 0);                   // 128 KB
  float*          wkf        = (float*)(ws + 131072);            // 128 KB
  int*            counts_eff = (int*)(ws + 262144);              // 256 B
  double*         c64        = (double*)(ws + 262400);           // 512 B
  int*            cand8      = (int*)(ws + 262912);              // 512 KB
  double*         Gt         = (double*)(ws + 787200);           // 1 MB
  unsigned short* G_bf       = (unsigned short*)(ws + 1835776);  // 256 KB
  int*            slots      = (int*)(ws + 2097920);             // 160 KB
  unsigned short* x_bf       = (unsigned short*)(ws + 2261760);  // 64 MB
  unsigned short* We_bf      = (unsigned short*)(ws + 69370624); // 8 MB
  unsigned short* U_bf       = (unsigned short*)(ws + 77759232); // 32 MB
  unsigned short* V_bf       = (unsigned short*)(ws + 111313664);// 32 MB
  unsigned short* Hbuf       = (unsigned short*)(ws + 144868096);// 10 MB
  // total ws use ~148.2 MB

  cvt_bf16_kernel<<<dim3(2048), 256, 0, stream>>>(x, x_bf, NTOK * DDIM / 4);
  cvt_bf16_kernel<<<dim3(2048), 256, 0, stream>>>(We, We_bf, DDIM * DDIM / 4);
  cvt_bf16_kernel<<<dim3(2048), 256, 0, stream>>>(U, U_bf, NEXP * RRANK * DDIM / 4);
  cvt_bf16_kernel<<<dim3(2048), 256, 0, stream>>>(V, V_bf, NEXP * DDIM * RRANK / 4);

  gmat_kernel<<<dim3(32), 256, 0, stream>>>(We, Wg, Gt, G_bf);
  bias_c_kernel<<<dim3(64), 256, 0, stream>>>(be, Wg, c64);
  logits_topc_kernel<<<dim3(128), 256, 0, stream>>>(x_bf, G_bf, c64, cand8);
  refine_kernel<<<dim3(NTOK), 256, 0, stream>>>(x, Gt, c64, cand8, topk, wkf);
  route_kernel<<<dim3(64), 256, 0, stream>>>(topk, wkf, slots, counts_eff);

  enc_mfma2<<<dim3(2048), 256, 0, stream>>>(x_bf, We_bf, be, y);
  expert_h_mfma<<<dim3(640), 256, 0, stream>>>(y, U_bf, counts_eff, slots, Hbuf);
  expert_out_mfma<<<dim3(640), 256, 0, stream>>>(Hbuf, V_bf, gamma, counts_eff, slots, wkf, y);
}

// Round 5
// 806.042 us; speedup vs baseline: 4.1888x; 1.2972x over previous
//
#include <hip/hip_runtime.h>
#include <math.h>

#define NTOK 16384
#define DDIM 2048
#define NEXP 64
#define RRANK 128
#define CAP 640  // ceil(1.25 * 32768 / 64)

typedef __attribute__((ext_vector_type(8))) short bf16x8;
typedef __attribute__((ext_vector_type(4))) float f32x4;
typedef __attribute__((address_space(1))) const unsigned int gu32_t;
typedef __attribute__((address_space(3))) unsigned int lu32_t;

__device__ __forceinline__ void gload16(const void* g, void* l) {
  __builtin_amdgcn_global_load_lds((gu32_t*)g, (lu32_t*)l, 16, 0, 0);
}

__device__ __forceinline__ float silu_f(float v) {
  return v / (1.f + expf(-v));
}

__device__ __forceinline__ unsigned short f2bf(float f) {
  unsigned int u = __float_as_uint(f);
  unsigned int r = (u + 0x7fffu + ((u >> 16) & 1u)) >> 16;
  return (unsigned short)r;
}

__device__ __forceinline__ float bf2f(unsigned short u) {
  return __uint_as_float(((unsigned int)u) << 16);
}

__device__ __forceinline__ int swz256(int d) {  // XOR-swizzle for 256B-row tiles
  return d ^ (((d >> 8) & 7) << 4);
}

// ---------------- fp32 -> bf16 bulk convert --------------------------------
__global__ __launch_bounds__(256) void cvt_bf16_kernel(
    const float* __restrict__ in, unsigned short* __restrict__ out, int n4)
{
  int i = blockIdx.x * 256 + threadIdx.x;
  const int stride = gridDim.x * 256;
  for (; i < n4; i += stride) {
    const float4 v = ((const float4*)in)[i];
    ushort4 o;
    o.x = f2bf(v.x); o.y = f2bf(v.y); o.z = f2bf(v.z); o.w = f2bf(v.w);
    ((ushort4*)out)[i] = o;
  }
}

// ---------------- encoder GEMM (bf16 MFMA): enc = x@We^T + be --------------
__global__ __launch_bounds__(256) void enc_mfma2(
    const unsigned short* __restrict__ xb, const unsigned short* __restrict__ Web,
    const float* __restrict__ be, float* __restrict__ out)
{
  __shared__ unsigned short At[128 * 32];
  __shared__ unsigned short Bt[128 * 32];
  const int tid = threadIdx.x;
  const int lane = tid & 63, wid = tid >> 6;
  const int wr = wid >> 1, wc = wid & 1;
  const int fr = lane & 15, fq = lane >> 4;
  const int bid = blockIdx.x;
  const int wg = (bid & 7) * 256 + (bid >> 3);  // bijective XCD swizzle
  const int n0 = (wg & 15) * 128, m0 = (wg >> 4) * 128;

  const int doff0 = wid * 1024 + lane * 16;
  const int doff1 = doff0 + 4096;
  const unsigned short* as0 = xb + (size_t)(m0 + (doff0 >> 6)) * DDIM + ((doff0 & 63) >> 1);
  const unsigned short* as1 = xb + (size_t)(m0 + (doff1 >> 6)) * DDIM + ((doff1 & 63) >> 1);
  const unsigned short* bs0 = Web + (size_t)(n0 + (doff0 >> 6)) * DDIM + ((doff0 & 63) >> 1);
  const unsigned short* bs1 = Web + (size_t)(n0 + (doff1 >> 6)) * DDIM + ((doff1 & 63) >> 1);
  char* ad0 = (char*)At + doff0; char* ad1 = (char*)At + doff1;
  char* bd0 = (char*)Bt + doff0; char* bd1 = (char*)Bt + doff1;

  f32x4 acc[4][4];
#pragma unroll
  for (int m = 0; m < 4; ++m)
#pragma unroll
    for (int n = 0; n < 4; ++n) acc[m][n] = (f32x4){0.f, 0.f, 0.f, 0.f};

  for (int kb = 0; kb < DDIM; kb += 32) {
    __syncthreads();
    gload16(as0 + kb, ad0);
    gload16(as1 + kb, ad1);
    gload16(bs0 + kb, bd0);
    gload16(bs1 + kb, bd1);
    __syncthreads();
    bf16x8 af[4], bfr[4];
#pragma unroll
    for (int m = 0; m < 4; ++m)
      af[m] = *(const bf16x8*)&At[(wr * 64 + m * 16 + fr) * 32 + fq * 8];
#pragma unroll
    for (int n = 0; n < 4; ++n)
      bfr[n] = *(const bf16x8*)&Bt[(wc * 64 + n * 16 + fr) * 32 + fq * 8];
#pragma unroll
    for (int m = 0; m < 4; ++m)
#pragma unroll
      for (int n = 0; n < 4; ++n)
        acc[m][n] = __builtin_amdgcn_mfma_f32_16x16x32_bf16(af[m], bfr[n], acc[m][n], 0, 0, 0);
  }

  float bias[4];
#pragma unroll
  for (int n = 0; n < 4; ++n) bias[n] = be[n0 + wc * 64 + n * 16 + fr];
#pragma unroll
  for (int m = 0; m < 4; ++m) {
#pragma unroll
    for (int j = 0; j < 4; ++j) {
      const int row = m0 + wr * 64 + m * 16 + fq * 4 + j;
      float* op = out + (size_t)row * DDIM + n0 + wc * 64 + fr;
#pragma unroll
      for (int n = 0; n < 4; ++n)
        op[n * 16] = acc[m][n][j] + bias[n];
    }
  }
}

// ------- G partials (fp64): Gpart[oc][e][d] over o-chunk oc ----------------
__global__ __launch_bounds__(256) void gmat_part_kernel(
    const float* __restrict__ We, const float* __restrict__ Wg,
    double* __restrict__ Gpart)
{
  __shared__ float As[64][68];  // [o][d]
  __shared__ float Bs[64][68];  // [o][e]
  const int tid = threadIdx.x;
  const int d0 = blockIdx.x * 64;
  const int oc = blockIdx.y;
  const int tx = tid & 15, ty = tid >> 4;
  const int row = tid >> 2, p = (tid & 3) * 16;

  double acc[4][4];
#pragma unroll
  for (int j = 0; j < 4; ++j)
#pragma unroll
    for (int i = 0; i < 4; ++i) acc[j][i] = 0.0;

  for (int o0 = oc * 256; o0 < oc * 256 + 256; o0 += 64) {
    float4 wv[4], gv[4];
#pragma unroll
    for (int q = 0; q < 4; ++q) {
      wv[q] = *(const float4*)(We + (size_t)(o0 + row) * DDIM + d0 + p + q * 4);
      gv[q] = *(const float4*)(Wg + (size_t)row * DDIM + o0 + p + q * 4);
    }
    __syncthreads();
#pragma unroll
    for (int q = 0; q < 4; ++q) {
      const int c = p + q * 4;
      As[row][c + 0] = wv[q].x; As[row][c + 1] = wv[q].y;
      As[row][c + 2] = wv[q].z; As[row][c + 3] = wv[q].w;
      Bs[c + 0][row] = gv[q].x; Bs[c + 1][row] = gv[q].y;
      Bs[c + 2][row] = gv[q].z; Bs[c + 3][row] = gv[q].w;
    }
    __syncthreads();
#pragma unroll 8
    for (int oo = 0; oo < 64; ++oo) {
      double a[4], b[4];
#pragma unroll
      for (int j = 0; j < 4; ++j) a[j] = (double)As[oo][ty * 4 + j];
#pragma unroll
      for (int i = 0; i < 4; ++i) b[i] = (double)Bs[oo][tx * 4 + i];
#pragma unroll
      for (int j = 0; j < 4; ++j)
#pragma unroll
        for (int i = 0; i < 4; ++i)
          acc[j][i] = fma(a[j], b[i], acc[j][i]);
    }
    __syncthreads();
  }
#pragma unroll
  for (int j = 0; j < 4; ++j)
#pragma unroll
    for (int i = 0; i < 4; ++i) {
      const int d = d0 + ty * 4 + j, e = tx * 4 + i;
      Gpart[(size_t)oc * (DDIM * NEXP) + (size_t)e * DDIM + d] = acc[j][i];
    }
}

// ------- reduce partials -> Gt (fp64) + G_bf (bf16) ------------------------
__global__ __launch_bounds__(256) void greduce_kernel(
    const double* __restrict__ Gpart, double* __restrict__ Gt,
    unsigned short* __restrict__ Gbf)
{
  const int idx = blockIdx.x * 256 + threadIdx.x;  // 131072 total
  double s = 0.0;
#pragma unroll
  for (int oc = 0; oc < 8; ++oc)
    s += Gpart[(size_t)oc * (DDIM * NEXP) + idx];
  Gt[idx] = s;
  Gbf[idx] = f2bf((float)s);
}

// ---------------- c[e] = be . Wg[e]  (fp64) --------------------------------
__global__ __launch_bounds__(256) void bias_c_kernel(
    const float* __restrict__ be, const float* __restrict__ Wg,
    double* __restrict__ c64)
{
  const int e = blockIdx.x;
  const int tid = threadIdx.x;
  double s = 0.0;
  for (int o = tid; o < DDIM; o += 256)
    s += (double)be[o] * (double)Wg[(size_t)e * DDIM + o];
  __shared__ double red[256];
  red[tid] = s;
  __syncthreads();
  for (int st = 128; st > 0; st >>= 1) {
    if (tid < st) red[tid] += red[tid + st];
    __syncthreads();
  }
  if (tid == 0) c64[e] = red[0];
}

// ---- approx logits (bf16 MFMA) + fused per-token top-8 candidates ---------
__global__ __launch_bounds__(256) void logits_topc_kernel(
    const unsigned short* __restrict__ xb, const unsigned short* __restrict__ Gbf,
    const double* __restrict__ c64, int* __restrict__ cand8)
{
  __shared__ unsigned short At[128 * 32];  // 8 KB: tokens x k
  __shared__ unsigned short Bt[64 * 32];   // 4 KB: experts x k
  __shared__ float Ls[128][64];            // 32 KB logits
  const int tid = threadIdx.x;
  const int lane = tid & 63, wid = tid >> 6;
  const int fr = lane & 15, fq = lane >> 4;
  const int t0 = blockIdx.x * 128;

  const int doff0 = wid * 1024 + lane * 16;  // == tid*16
  const int doff1 = doff0 + 4096;
  const unsigned short* as0 = xb + (size_t)(t0 + (doff0 >> 6)) * DDIM + ((doff0 & 63) >> 1);
  const unsigned short* as1 = xb + (size_t)(t0 + (doff1 >> 6)) * DDIM + ((doff1 & 63) >> 1);
  const unsigned short* bs0 = Gbf + (size_t)(doff0 >> 6) * DDIM + ((doff0 & 63) >> 1);
  char* ad0 = (char*)At + doff0; char* ad1 = (char*)At + doff1;
  char* bd0 = (char*)Bt + doff0;

  f32x4 acc[2][4];
#pragma unroll
  for (int m = 0; m < 2; ++m)
#pragma unroll
    for (int n = 0; n < 4; ++n) acc[m][n] = (f32x4){0.f, 0.f, 0.f, 0.f};

  for (int kb = 0; kb < DDIM; kb += 32) {
    __syncthreads();
    gload16(as0 + kb, ad0);
    gload16(as1 + kb, ad1);
    gload16(bs0 + kb, bd0);
    __syncthreads();
    bf16x8 af[2], bfr[4];
#pragma unroll
    for (int m = 0; m < 2; ++m)
      af[m] = *(const bf16x8*)&At[(wid * 32 + m * 16 + fr) * 32 + fq * 8];
#pragma unroll
    for (int n = 0; n < 4; ++n)
      bfr[n] = *(const bf16x8*)&Bt[(n * 16 + fr) * 32 + fq * 8];
#pragma unroll
    for (int m = 0; m < 2; ++m)
#pragma unroll
      for (int n = 0; n < 4; ++n)
        acc[m][n] = __builtin_amdgcn_mfma_f32_16x16x32_bf16(af[m], bfr[n], acc[m][n], 0, 0, 0);
  }

#pragma unroll
  for (int m = 0; m < 2; ++m)
#pragma unroll
    for (int j = 0; j < 4; ++j) {
      const int row = wid * 32 + m * 16 + fq * 4 + j;
#pragma unroll
      for (int n = 0; n < 4; ++n)
        Ls[row][n * 16 + fr] = acc[m][n][j];
    }
  __syncthreads();

  if (tid < 128) {
    float v8[8];
    int i8[8];
#pragma unroll
    for (int c = 0; c < 8; ++c) { v8[c] = -INFINITY; i8[c] = 0; }
    for (int e = 0; e < NEXP; ++e) {
      const float v = Ls[tid][e] + (float)c64[e];
      if (v > v8[7]) {
        int p = 7;
        while (p > 0 && v > v8[p - 1]) { v8[p] = v8[p - 1]; i8[p] = i8[p - 1]; --p; }
        v8[p] = v; i8[p] = e;
      }
    }
    int* cp = cand8 + (size_t)(t0 + tid) * 8;
#pragma unroll
    for (int c = 0; c < 8; ++c) cp[c] = i8[c];
  }
}

// ---- exact fp64 refine of 8 candidates: top-2 + softmax -------------------
__global__ __launch_bounds__(256) void refine_kernel(
    const float* __restrict__ x, const double* __restrict__ Gt,
    const double* __restrict__ c64, const int* __restrict__ cand8,
    int* __restrict__ topk, float* __restrict__ wkf)
{
  const int t = blockIdx.x;
  const int tid = threadIdx.x;
  const int lane = tid & 63, w = tid >> 6;
  __shared__ float xs[DDIM];
  __shared__ double red[8][4];

  ((float4*)xs)[tid] = ((const float4*)(x + (size_t)t * DDIM))[tid];
  ((float4*)xs)[tid + 256] = ((const float4*)(x + (size_t)t * DDIM))[tid + 256];
  __syncthreads();

  int myc[8];
#pragma unroll
  for (int c = 0; c < 8; ++c) myc[c] = cand8[(size_t)t * 8 + c];

#pragma unroll
  for (int c = 0; c < 8; ++c) {
    const double* g = Gt + (size_t)myc[c] * DDIM;
    double s = 0.0;
#pragma unroll
    for (int q = 0; q < 8; ++q) {
      const int d = q * 256 + tid;
      s += (double)xs[d] * g[d];
    }
#pragma unroll
    for (int off = 32; off > 0; off >>= 1) s += __shfl_down(s, off);
    if (lane == 0) red[c][w] = s;
  }
  __syncthreads();

  if (tid == 0) {
    double v1 = -1e300, v2 = -1e300;
    int i1 = 0, i2 = 0;
#pragma unroll
    for (int c = 0; c < 8; ++c) {
      const double v = red[c][0] + red[c][1] + red[c][2] + red[c][3] + c64[myc[c]];
      if (v > v1) { v2 = v1; i2 = i1; v1 = v; i1 = myc[c]; }
      else if (v > v2) { v2 = v; i2 = myc[c]; }
    }
    const double e2 = exp(v2 - v1);
    const double s = 1.0 + e2 + 1e-12;
    topk[2 * t] = i1; topk[2 * t + 1] = i2;
    wkf[2 * t] = (float)(1.0 / s);
    wkf[2 * t + 1] = (float)(e2 / s);
  }
}

// ------- deterministic capacity routing: rank in token order, drop >= CAP --
__global__ __launch_bounds__(256) void route_kernel(
    const int* __restrict__ topk, const float* __restrict__ wkf,
    int* __restrict__ slots /* [NEXP][CAP] */, int* __restrict__ counts_eff,
    int* __restrict__ val /* [N] pre-zeroed */)
{
  const int e = blockIdx.x;
  const int tid = threadIdx.x;
  const int lane = tid & 63, wave = tid >> 6;
  __shared__ int wcnt[4];
  __shared__ int sbase;
  if (tid == 0) sbase = 0;
  __syncthreads();

  for (int c0 = 0; c0 < NTOK * 2; c0 += 256) {
    const int a = c0 + tid;
    const bool match = (topk[a] == e) && (wkf[a] > 1e-12f);
    const unsigned long long bal = __ballot(match);
    if (lane == 0) wcnt[wave] = __popcll(bal);
    __syncthreads();
    int base = sbase;
    for (int w = 0; w < 4; ++w)
      if (w < wave) base += wcnt[w];
    const int rank = base + (int)__popcll(bal & ((1ull << lane) - 1ull));
    if (match && rank < CAP) {
      slots[e * CAP + rank] = a;
      val[a] = 1;
    }
    __syncthreads();
    if (tid == 0) sbase += wcnt[0] + wcnt[1] + wcnt[2] + wcnt[3];
  }
  __syncthreads();
  if (tid == 0) counts_eff[e] = (sbase < CAP) ? sbase : CAP;
}

// -------- expert pass 1 (bf16 MFMA): H[slot][r] = silu(U_e @ enc[tok]) ----
__global__ __launch_bounds__(256) void expert_h_mfma(
    const float* __restrict__ enc, const unsigned short* __restrict__ Ub,
    const int* __restrict__ counts_eff, const int* __restrict__ slots,
    unsigned short* __restrict__ Hbuf)
{
  const int lin = blockIdx.x;                   // 640 wgs
  const int wg = (lin & 7) * 80 + (lin >> 3);   // XCD swizzle: expert locality
  const int e = wg / 10;
  const int t0 = (wg % 10) * 64;
  const int cnt = counts_eff[e];
  if (t0 >= cnt) return;
  __shared__ unsigned short At[64 * 32];   // tokens x k
  __shared__ unsigned short Bt[128 * 32];  // r x k
  __shared__ int toks[64];
  const int tid = threadIdx.x;
  const int lane = tid & 63, wid = tid >> 6;
  const int wr = wid >> 1, wc = wid & 1;
  const int fr = lane & 15, fq = lane >> 4;

  if (tid < 64) {
    const int i = t0 + tid;
    toks[tid] = (i < cnt) ? (slots[e * CAP + i] >> 1) : (slots[e * CAP] >> 1);
  }
  __syncthreads();

  const int arow = tid >> 2, ak0 = (tid & 3) * 8;
  const float* ap = enc + (size_t)toks[arow] * DDIM + ak0;
  unsigned short* awp = &At[arow * 32 + ak0];

  const int doff0 = wid * 1024 + lane * 16;
  const int doff1 = doff0 + 4096;
  const unsigned short* Ue = Ub + (size_t)e * RRANK * DDIM;
  const unsigned short* bsrc0 = Ue + (size_t)(doff0 >> 6) * DDIM + ((doff0 & 63) >> 1);
  const unsigned short* bsrc1 = Ue + (size_t)(doff1 >> 6) * DDIM + ((doff1 & 63) >> 1);
  unsigned short* bdst0 = (unsigned short*)((char*)Bt + doff0);
  unsigned short* bdst1 = (unsigned short*)((char*)Bt + doff1);

  f32x4 acc[2][4];
#pragma unroll
  for (int m = 0; m < 2; ++m)
#pragma unroll
    for (int n = 0; n < 4; ++n) acc[m][n] = (f32x4){0.f, 0.f, 0.f, 0.f};

  float4 a0 = *(const float4*)(ap), a1 = *(const float4*)(ap + 4);

  for (int kb = 0; kb < DDIM; kb += 32) {
    __syncthreads();
    union { unsigned short us[8]; uint4 q; } pk;
    pk.us[0] = f2bf(a0.x); pk.us[1] = f2bf(a0.y);
    pk.us[2] = f2bf(a0.z); pk.us[3] = f2bf(a0.w);
    pk.us[4] = f2bf(a1.x); pk.us[5] = f2bf(a1.y);
    pk.us[6] = f2bf(a1.z); pk.us[7] = f2bf(a1.w);
    *(uint4*)awp = pk.q;
    gload16(bsrc0 + kb, bdst0);
    gload16(bsrc1 + kb, bdst1);
    __syncthreads();
    if (kb + 32 < DDIM) {
      a0 = *(const float4*)(ap + kb + 32);
      a1 = *(const float4*)(ap + kb + 36);
    }
    bf16x8 af[2], bfr[4];
#pragma unroll
    for (int m = 0; m < 2; ++m)
      af[m] = *(const bf16x8*)&At[(wr * 32 + m * 16 + fr) * 32 + fq * 8];
#pragma unroll
    for (int n = 0; n < 4; ++n)
      bfr[n] = *(const bf16x8*)&Bt[(wc * 64 + n * 16 + fr) * 32 + fq * 8];
#pragma unroll
    for (int m = 0; m < 2; ++m)
#pragma unroll
      for (int n = 0; n < 4; ++n)
        acc[m][n] = __builtin_amdgcn_mfma_f32_16x16x32_bf16(af[m], bfr[n], acc[m][n], 0, 0, 0);
  }

#pragma unroll
  for (int m = 0; m < 2; ++m) {
#pragma unroll
    for (int j = 0; j < 4; ++j) {
      const int tl = wr * 32 + m * 16 + fq * 4 + j;
      if (t0 + tl < cnt) {
        unsigned short* hp = Hbuf + (size_t)(e * CAP + t0 + tl) * RRANK + wc * 64 + fr;
#pragma unroll
        for (int n = 0; n < 4; ++n)
          hp[n * 16] = f2bf(silu_f(acc[m][n][j]));
      }
    }
  }
}

// -------- expert pass 2 (bf16 MFMA): Dbuf[a] = w*gamma*(H @ V_e^T) ---------
__global__ __launch_bounds__(256) void expert_out_mfma(
    const unsigned short* __restrict__ Hbuf, const unsigned short* __restrict__ Vb,
    const float* __restrict__ gamma, const int* __restrict__ counts_eff,
    const int* __restrict__ slots, const float* __restrict__ wkf,
    unsigned short* __restrict__ Dbuf)
{
  const int lin = blockIdx.x;                   // 640 wgs
  const int wg = (lin & 7) * 80 + (lin >> 3);   // XCD swizzle: expert locality
  const int e = wg / 10;
  const int t0 = (wg % 10) * 64;
  const int cnt = counts_eff[e];
  if (t0 >= cnt) return;
  __shared__ unsigned short Ht[64 * 128];   // tokens x r (swizzled)
  __shared__ unsigned short Vt[128 * 128];  // d x r (swizzled)
  __shared__ int aid[64];
  __shared__ float wts[64];
  const int tid = threadIdx.x;
  const int lane = tid & 63, wid = tid >> 6;
  const int wr = wid >> 1, wc = wid & 1;
  const int fr = lane & 15, fq = lane >> 4;

  if (tid < 64) {
    const int i = t0 + tid;
    if (i < cnt) {
      const int a = slots[e * CAP + i];
      aid[tid] = a;
      wts[tid] = wkf[a] * gamma[e];
    } else { aid[tid] = -1; wts[tid] = 0.f; }
  }

  // stage Ht: contiguous 16 KB, linear dest + swizzled source
  const unsigned short* hsrc = Hbuf + (size_t)(e * CAP + t0) * RRANK;
  const int hd = wid * 1024 + lane * 16;
#pragma unroll
  for (int is = 0; is < 4; ++is) {
    const int d = is * 4096 + hd;
    gload16(hsrc + (swz256(d) >> 1), (char*)Ht + d);
  }

  const unsigned short* vsrc0 = Vb + (size_t)e * DDIM * RRANK;

  bf16x8 af[2][4];
  float wv[2][4];
  int av[2][4];

  for (int nb = 0; nb < 16; ++nb) {
    __syncthreads();
    const unsigned short* vsrc = vsrc0 + (size_t)nb * 128 * RRANK;
#pragma unroll
    for (int is = 0; is < 8; ++is) {
      const int d = is * 4096 + hd;
      gload16(vsrc + (swz256(d) >> 1), (char*)Vt + d);
    }
    __syncthreads();
    if (nb == 0) {
#pragma unroll
      for (int m = 0; m < 2; ++m) {
        const int row = wr * 32 + m * 16 + fr;
#pragma unroll
        for (int kk = 0; kk < 4; ++kk) {
          const int b = (row * 256 + kk * 64 + fq * 16) ^ ((row & 7) << 4);
          af[m][kk] = *(const bf16x8*)((const char*)Ht + b);
        }
#pragma unroll
        for (int j = 0; j < 4; ++j) {
          const int tl = wr * 32 + m * 16 + fq * 4 + j;
          wv[m][j] = wts[tl];
          av[m][j] = (t0 + tl < cnt) ? aid[tl] : -1;
        }
      }
    }

    f32x4 acc[2][4];
#pragma unroll
    for (int m = 0; m < 2; ++m)
#pragma unroll
      for (int n = 0; n < 4; ++n) acc[m][n] = (f32x4){0.f, 0.f, 0.f, 0.f};

#pragma unroll
    for (int n = 0; n < 4; ++n) {
      const int drow = wc * 64 + n * 16 + fr;
#pragma unroll
      for (int kk = 0; kk < 4; ++kk) {
        const int b = (drow * 256 + kk * 64 + fq * 16) ^ ((drow & 7) << 4);
        const bf16x8 bfr = *(const bf16x8*)((const char*)Vt + b);
#pragma unroll
        for (int m = 0; m < 2; ++m)
          acc[m][n] = __builtin_amdgcn_mfma_f32_16x16x32_bf16(af[m][kk], bfr, acc[m][n], 0, 0, 0);
      }
    }

#pragma unroll
    for (int m = 0; m < 2; ++m) {
#pragma unroll
      for (int j = 0; j < 4; ++j) {
        if (av[m][j] >= 0) {
          const float w = wv[m][j];
          unsigned short* dp = Dbuf + (size_t)av[m][j] * DDIM + nb * 128 + wc * 64 + fr;
#pragma unroll
          for (int n = 0; n < 4; ++n)
            dp[n * 16] = f2bf(acc[m][n][j] * w);
        }
      }
    }
  }
}

// -------- combine: y[t] = enc[t] + Dbuf[2t] + Dbuf[2t+1] -------------------
__global__ __launch_bounds__(256) void combine_kernel(
    const unsigned short* __restrict__ Dbuf, const int* __restrict__ val,
    float* __restrict__ y)
{
  const int t = blockIdx.x;
  const int tid = threadIdx.x;
  const int c0 = tid * 8;
  float* yp = y + (size_t)t * DDIM + c0;
  const int v0 = val[2 * t], v1 = val[2 * t + 1];

  float4 o0 = *(const float4*)(yp);
  float4 o1 = *(const float4*)(yp + 4);
  float o[8] = {o0.x, o0.y, o0.z, o0.w, o1.x, o1.y, o1.z, o1.w};

  if (v0) {
    const ushort4 d0 = *(const ushort4*)(Dbuf + (size_t)(2 * t) * DDIM + c0);
    const ushort4 d1 = *(const ushort4*)(Dbuf + (size_t)(2 * t) * DDIM + c0 + 4);
    o[0] += bf2f(d0.x); o[1] += bf2f(d0.y); o[2] += bf2f(d0.z); o[3] += bf2f(d0.w);
    o[4] += bf2f(d1.x); o[5] += bf2f(d1.y); o[6] += bf2f(d1.z); o[7] += bf2f(d1.w);
  }
  if (v1) {
    const ushort4 d0 = *(const ushort4*)(Dbuf + (size_t)(2 * t + 1) * DDIM + c0);
    const ushort4 d1 = *(const ushort4*)(Dbuf + (size_t)(2 * t + 1) * DDIM + c0 + 4);
    o[0] += bf2f(d0.x); o[1] += bf2f(d0.y); o[2] += bf2f(d0.z); o[3] += bf2f(d0.w);
    o[4] += bf2f(d1.x); o[5] += bf2f(d1.y); o[6] += bf2f(d1.z); o[7] += bf2f(d1.w);
  }
  *(float4*)(yp) = (float4){o[0], o[1], o[2], o[3]};
  *(float4*)(yp + 4) = (float4){o[4], o[5], o[6], o[7]};
}

extern "C" void kernel_launch(void* const* d_in, const int* in_sizes, int n_in,
                              void* d_out, int out_size, void* d_ws, size_t ws_size,
                              hipStream_t stream)
{
  const float* x     = (const float*)d_in[0];
  const float* We    = (const float*)d_in[1];
  const float* be    = (const float*)d_in[2];
  const float* Wg    = (const float*)d_in[3];
  const float* U     = (const float*)d_in[4];
  const float* V     = (const float*)d_in[5];
  const float* gamma = (const float*)d_in[6];
  float* y = (float*)d_out;

  char* ws = (char*)d_ws;
  int*            topk       = (int*)(ws + 0);                   // 128 KB
  float*          wkf        = (float*)(ws + 131072);            // 128 KB
  int*            counts_eff = (int*)(ws + 262144);              // 256 B
  double*         c64        = (double*)(ws + 262400);           // 512 B
  int*            cand8      = (int*)(ws + 262912);              // 512 KB
  double*         Gt         = (double*)(ws + 787200);           // 1 MB
  unsigned short* G_bf       = (unsigned short*)(ws + 1835776);  // 256 KB
  int*            slots      = (int*)(ws + 2097920);             // 160 KB
  int*            val        = (int*)(ws + 2261760);             // 128 KB
  double*         Gpart      = (double*)(ws + 2392832);          // 8 MB
  unsigned short* x_bf       = (unsigned short*)(ws + 10781952); // 64 MB
  unsigned short* We_bf      = (unsigned short*)(ws + 77890816); // 8 MB
  unsigned short* U_bf       = (unsigned short*)(ws + 86279424); // 32 MB
  unsigned short* V_bf       = (unsigned short*)(ws + 119833856);// 32 MB
  unsigned short* Hbuf       = (unsigned short*)(ws + 153388288);// 10 MB
  unsigned short* Dbuf       = (unsigned short*)(ws + 163874048);// 128 MB
  // total ws use ~284.3 MB

  hipMemsetAsync(val, 0, 131072, stream);

  cvt_bf16_kernel<<<dim3(2048), 256, 0, stream>>>(x, x_bf, NTOK * DDIM / 4);
  cvt_bf16_kernel<<<dim3(2048), 256, 0, stream>>>(We, We_bf, DDIM * DDIM / 4);
  cvt_bf16_kernel<<<dim3(2048), 256, 0, stream>>>(U, U_bf, NEXP * RRANK * DDIM / 4);
  cvt_bf16_kernel<<<dim3(2048), 256, 0, stream>>>(V, V_bf, NEXP * DDIM * RRANK / 4);

  gmat_part_kernel<<<dim3(32, 8), 256, 0, stream>>>(We, Wg, Gpart);
  greduce_kernel<<<dim3(512), 256, 0, stream>>>(Gpart, Gt, G_bf);
  bias_c_kernel<<<dim3(64), 256, 0, stream>>>(be, Wg, c64);
  logits_topc_kernel<<<dim3(128), 256, 0, stream>>>(x_bf, G_bf, c64, cand8);
  refine_kernel<<<dim3(NTOK), 256, 0, stream>>>(x, Gt, c64, cand8, topk, wkf);
  route_kernel<<<dim3(64), 256, 0, stream>>>(topk, wkf, slots, counts_eff, val);

  enc_mfma2<<<dim3(2048), 256, 0, stream>>>(x_bf, We_bf, be, y);
  expert_h_mfma<<<dim3(640), 256, 0, stream>>>(y, U_bf, counts_eff, slots, Hbuf);
  expert_out_mfma<<<dim3(640), 256, 0, stream>>>(Hbuf, V_bf, gamma, counts_eff, slots, wkf, Dbuf);
  combine_kernel<<<dim3(NTOK), 256, 0, stream>>>(Dbuf, val, y);
}

// Round 6
// 796.451 us; speedup vs baseline: 4.2392x; 1.0120x over previous
//
#include <hip/hip_runtime.h>
#include <math.h>

#define NTOK 16384
#define DDIM 2048
#define NEXP 64
#define RRANK 128
#define CAP 640  // ceil(1.25 * 32768 / 64)

typedef __attribute__((ext_vector_type(8))) short bf16x8;
typedef __attribute__((ext_vector_type(4))) float f32x4;
typedef __attribute__((address_space(1))) const unsigned int gu32_t;
typedef __attribute__((address_space(3))) unsigned int lu32_t;

__device__ __forceinline__ void gload16(const void* g, void* l) {
  __builtin_amdgcn_global_load_lds((gu32_t*)g, (lu32_t*)l, 16, 0, 0);
}

__device__ __forceinline__ float silu_f(float v) {
  return v / (1.f + expf(-v));
}

__device__ __forceinline__ unsigned short f2bf(float f) {
  unsigned int u = __float_as_uint(f);
  unsigned int r = (u + 0x7fffu + ((u >> 16) & 1u)) >> 16;
  return (unsigned short)r;
}

__device__ __forceinline__ float bf2f(unsigned short u) {
  return __uint_as_float(((unsigned int)u) << 16);
}

__device__ __forceinline__ int swz256(int d) {  // XOR-swizzle for 256B-row tiles
  return d ^ (((d >> 8) & 7) << 4);
}

// ---------------- fp32 -> bf16 bulk convert (all 4 tensors, 1 launch) ------
__global__ __launch_bounds__(256) void cvt_all_kernel(
    const float* __restrict__ x, const float* __restrict__ We,
    const float* __restrict__ U, const float* __restrict__ V,
    unsigned short* __restrict__ xb, unsigned short* __restrict__ Web,
    unsigned short* __restrict__ Ub, unsigned short* __restrict__ Vb)
{
  const int S0 = NTOK * DDIM / 4;
  const int S1 = DDIM * DDIM / 4;
  const int S2 = NEXP * RRANK * DDIM / 4;
  const int total = S0 + S1 + 2 * S2;
  int i = blockIdx.x * 256 + threadIdx.x;
  const int stride = gridDim.x * 256;
  for (; i < total; i += stride) {
    const float* in; unsigned short* out; int j;
    if (i < S0) { in = x; out = xb; j = i; }
    else if (i < S0 + S1) { in = We; out = Web; j = i - S0; }
    else if (i < S0 + S1 + S2) { in = U; out = Ub; j = i - S0 - S1; }
    else { in = V; out = Vb; j = i - S0 - S1 - S2; }
    const float4 v = ((const float4*)in)[j];
    ushort4 o;
    o.x = f2bf(v.x); o.y = f2bf(v.y); o.z = f2bf(v.z); o.w = f2bf(v.w);
    ((ushort4*)out)[j] = o;
  }
}

// ---------------- encoder GEMM (bf16 MFMA, BK=64, XOR-swizzled LDS) --------
// enc = x@We^T + be ; writes fp32 y AND bf16 enc_bf
__global__ __launch_bounds__(256) void enc_mfma3(
    const unsigned short* __restrict__ xb, const unsigned short* __restrict__ Web,
    const float* __restrict__ be, float* __restrict__ out,
    unsigned short* __restrict__ encbf)
{
  __shared__ unsigned short At[128 * 64];  // 16 KB (chunk-swizzled)
  __shared__ unsigned short Bt[128 * 64];  // 16 KB
  const int tid = threadIdx.x;
  const int lane = tid & 63, wid = tid >> 6;
  const int wr = wid >> 1, wc = wid & 1;
  const int fr = lane & 15, fq = lane >> 4;
  const int bid = blockIdx.x;
  const int wg = (bid & 7) * 256 + (bid >> 3);  // bijective XCD swizzle
  const int n0 = (wg & 15) * 128, m0 = (wg >> 4) * 128;

  // staging: 4 issues x 256thr x 16B per tile; linear LDS dest, swizzled src
  const unsigned short* asrc[4];
  const unsigned short* bsrc[4];
  char* adst[4];
  char* bdst[4];
#pragma unroll
  for (int is = 0; is < 4; ++is) {
    const int doff = is * 4096 + tid * 16;
    const int r = doff >> 7;                 // 128B rows
    const int cs = ((doff >> 4) & 7) ^ (r & 7);
    asrc[is] = xb + (size_t)(m0 + r) * DDIM + cs * 8;
    bsrc[is] = Web + (size_t)(n0 + r) * DDIM + cs * 8;
    adst[is] = (char*)At + doff;
    bdst[is] = (char*)Bt + doff;
  }

  f32x4 acc[4][4];
#pragma unroll
  for (int m = 0; m < 4; ++m)
#pragma unroll
    for (int n = 0; n < 4; ++n) acc[m][n] = (f32x4){0.f, 0.f, 0.f, 0.f};

  for (int kb = 0; kb < DDIM; kb += 64) {
    __syncthreads();
#pragma unroll
    for (int is = 0; is < 4; ++is) {
      gload16(asrc[is] + kb, adst[is]);
      gload16(bsrc[is] + kb, bdst[is]);
    }
    __syncthreads();
#pragma unroll
    for (int kk = 0; kk < 2; ++kk) {
      bf16x8 af[4], bfv[4];
#pragma unroll
      for (int m = 0; m < 4; ++m) {
        const int row = wr * 64 + m * 16 + fr;
        af[m] = *(const bf16x8*)((const char*)At +
                 row * 128 + (((kk * 4 + fq) ^ (row & 7)) << 4));
      }
#pragma unroll
      for (int n = 0; n < 4; ++n) {
        const int row = wc * 64 + n * 16 + fr;
        bfv[n] = *(const bf16x8*)((const char*)Bt +
                  row * 128 + (((kk * 4 + fq) ^ (row & 7)) << 4));
      }
#pragma unroll
      for (int m = 0; m < 4; ++m)
#pragma unroll
        for (int n = 0; n < 4; ++n)
          acc[m][n] = __builtin_amdgcn_mfma_f32_16x16x32_bf16(af[m], bfv[n], acc[m][n], 0, 0, 0);
    }
  }

  float bias[4];
#pragma unroll
  for (int n = 0; n < 4; ++n) bias[n] = be[n0 + wc * 64 + n * 16 + fr];
#pragma unroll
  for (int m = 0; m < 4; ++m) {
#pragma unroll
    for (int j = 0; j < 4; ++j) {
      const int row = m0 + wr * 64 + m * 16 + fq * 4 + j;
      const size_t base = (size_t)row * DDIM + n0 + wc * 64 + fr;
      float* op = out + base;
      unsigned short* ob = encbf + base;
#pragma unroll
      for (int n = 0; n < 4; ++n) {
        const float v = acc[m][n][j] + bias[n];
        op[n * 16] = v;
        ob[n * 16] = f2bf(v);
      }
    }
  }
}

// ------- G partials (fp64): Gpart[oc][e][d] over o-chunk oc ----------------
__global__ __launch_bounds__(256) void gmat_part_kernel(
    const float* __restrict__ We, const float* __restrict__ Wg,
    double* __restrict__ Gpart)
{
  __shared__ float As[64][68];  // [o][d]
  __shared__ float Bs[64][68];  // [o][e]
  const int tid = threadIdx.x;
  const int d0 = blockIdx.x * 64;
  const int oc = blockIdx.y;
  const int tx = tid & 15, ty = tid >> 4;
  const int row = tid >> 2, p = (tid & 3) * 16;

  double acc[4][4];
#pragma unroll
  for (int j = 0; j < 4; ++j)
#pragma unroll
    for (int i = 0; i < 4; ++i) acc[j][i] = 0.0;

  for (int o0 = oc * 256; o0 < oc * 256 + 256; o0 += 64) {
    float4 wv[4], gv[4];
#pragma unroll
    for (int q = 0; q < 4; ++q) {
      wv[q] = *(const float4*)(We + (size_t)(o0 + row) * DDIM + d0 + p + q * 4);
      gv[q] = *(const float4*)(Wg + (size_t)row * DDIM + o0 + p + q * 4);
    }
    __syncthreads();
#pragma unroll
    for (int q = 0; q < 4; ++q) {
      const int c = p + q * 4;
      As[row][c + 0] = wv[q].x; As[row][c + 1] = wv[q].y;
      As[row][c + 2] = wv[q].z; As[row][c + 3] = wv[q].w;
      Bs[c + 0][row] = gv[q].x; Bs[c + 1][row] = gv[q].y;
      Bs[c + 2][row] = gv[q].z; Bs[c + 3][row] = gv[q].w;
    }
    __syncthreads();
#pragma unroll 8
    for (int oo = 0; oo < 64; ++oo) {
      double a[4], b[4];
#pragma unroll
      for (int j = 0; j < 4; ++j) a[j] = (double)As[oo][ty * 4 + j];
#pragma unroll
      for (int i = 0; i < 4; ++i) b[i] = (double)Bs[oo][tx * 4 + i];
#pragma unroll
      for (int j = 0; j < 4; ++j)
#pragma unroll
        for (int i = 0; i < 4; ++i)
          acc[j][i] = fma(a[j], b[i], acc[j][i]);
    }
    __syncthreads();
  }
#pragma unroll
  for (int j = 0; j < 4; ++j)
#pragma unroll
    for (int i = 0; i < 4; ++i) {
      const int d = d0 + ty * 4 + j, e = tx * 4 + i;
      Gpart[(size_t)oc * (DDIM * NEXP) + (size_t)e * DDIM + d] = acc[j][i];
    }
}

// ------- reduce partials -> Gt (fp64) + G_bf (bf16) ------------------------
__global__ __launch_bounds__(256) void greduce_kernel(
    const double* __restrict__ Gpart, double* __restrict__ Gt,
    unsigned short* __restrict__ Gbf)
{
  const int idx = blockIdx.x * 256 + threadIdx.x;  // 131072 total
  double s = 0.0;
#pragma unroll
  for (int oc = 0; oc < 8; ++oc)
    s += Gpart[(size_t)oc * (DDIM * NEXP) + idx];
  Gt[idx] = s;
  Gbf[idx] = f2bf((float)s);
}

// ---------------- c[e] = be . Wg[e]  (fp64) --------------------------------
__global__ __launch_bounds__(256) void bias_c_kernel(
    const float* __restrict__ be, const float* __restrict__ Wg,
    double* __restrict__ c64)
{
  const int e = blockIdx.x;
  const int tid = threadIdx.x;
  double s = 0.0;
  for (int o = tid; o < DDIM; o += 256)
    s += (double)be[o] * (double)Wg[(size_t)e * DDIM + o];
  __shared__ double red[256];
  red[tid] = s;
  __syncthreads();
  for (int st = 128; st > 0; st >>= 1) {
    if (tid < st) red[tid] += red[tid + st];
    __syncthreads();
  }
  if (tid == 0) c64[e] = red[0];
}

// ---- approx logits (bf16 MFMA) + fused per-token top-8 candidates ---------
__global__ __launch_bounds__(256) void logits_topc_kernel(
    const unsigned short* __restrict__ xb, const unsigned short* __restrict__ Gbf,
    const double* __restrict__ c64, int* __restrict__ cand8)
{
  __shared__ unsigned short At[128 * 32];  // 8 KB: tokens x k
  __shared__ unsigned short Bt[64 * 32];   // 4 KB: experts x k
  __shared__ float Ls[128][64];            // 32 KB logits
  const int tid = threadIdx.x;
  const int lane = tid & 63, wid = tid >> 6;
  const int fr = lane & 15, fq = lane >> 4;
  const int t0 = blockIdx.x * 128;

  const int doff0 = wid * 1024 + lane * 16;  // == tid*16
  const int doff1 = doff0 + 4096;
  const unsigned short* as0 = xb + (size_t)(t0 + (doff0 >> 6)) * DDIM + ((doff0 & 63) >> 1);
  const unsigned short* as1 = xb + (size_t)(t0 + (doff1 >> 6)) * DDIM + ((doff1 & 63) >> 1);
  const unsigned short* bs0 = Gbf + (size_t)(doff0 >> 6) * DDIM + ((doff0 & 63) >> 1);
  char* ad0 = (char*)At + doff0; char* ad1 = (char*)At + doff1;
  char* bd0 = (char*)Bt + doff0;

  f32x4 acc[2][4];
#pragma unroll
  for (int m = 0; m < 2; ++m)
#pragma unroll
    for (int n = 0; n < 4; ++n) acc[m][n] = (f32x4){0.f, 0.f, 0.f, 0.f};

  for (int kb = 0; kb < DDIM; kb += 32) {
    __syncthreads();
    gload16(as0 + kb, ad0);
    gload16(as1 + kb, ad1);
    gload16(bs0 + kb, bd0);
    __syncthreads();
    bf16x8 af[2], bfr[4];
#pragma unroll
    for (int m = 0; m < 2; ++m)
      af[m] = *(const bf16x8*)&At[(wid * 32 + m * 16 + fr) * 32 + fq * 8];
#pragma unroll
    for (int n = 0; n < 4; ++n)
      bfr[n] = *(const bf16x8*)&Bt[(n * 16 + fr) * 32 + fq * 8];
#pragma unroll
    for (int m = 0; m < 2; ++m)
#pragma unroll
      for (int n = 0; n < 4; ++n)
        acc[m][n] = __builtin_amdgcn_mfma_f32_16x16x32_bf16(af[m], bfr[n], acc[m][n], 0, 0, 0);
  }

#pragma unroll
  for (int m = 0; m < 2; ++m)
#pragma unroll
    for (int j = 0; j < 4; ++j) {
      const int row = wid * 32 + m * 16 + fq * 4 + j;
#pragma unroll
      for (int n = 0; n < 4; ++n)
        Ls[row][n * 16 + fr] = acc[m][n][j];
    }
  __syncthreads();

  if (tid < 128) {
    float v8[8];
    int i8[8];
#pragma unroll
    for (int c = 0; c < 8; ++c) { v8[c] = -INFINITY; i8[c] = 0; }
    for (int e = 0; e < NEXP; ++e) {
      const float v = Ls[tid][e] + (float)c64[e];
      if (v > v8[7]) {
        int p = 7;
        while (p > 0 && v > v8[p - 1]) { v8[p] = v8[p - 1]; i8[p] = i8[p - 1]; --p; }
        v8[p] = v; i8[p] = e;
      }
    }
    int* cp = cand8 + (size_t)(t0 + tid) * 8;
#pragma unroll
    for (int c = 0; c < 8; ++c) cp[c] = i8[c];
  }
}

// ---- exact fp64 refine of 8 candidates: top-2 + softmax -------------------
__global__ __launch_bounds__(256) void refine_kernel(
    const float* __restrict__ x, const double* __restrict__ Gt,
    const double* __restrict__ c64, const int* __restrict__ cand8,
    int* __restrict__ topk, float* __restrict__ wkf)
{
  const int t = blockIdx.x;
  const int tid = threadIdx.x;
  const int lane = tid & 63, w = tid >> 6;
  __shared__ float xs[DDIM];
  __shared__ double red[8][4];

  ((float4*)xs)[tid] = ((const float4*)(x + (size_t)t * DDIM))[tid];
  ((float4*)xs)[tid + 256] = ((const float4*)(x + (size_t)t * DDIM))[tid + 256];
  __syncthreads();

  int myc[8];
#pragma unroll
  for (int c = 0; c < 8; ++c) myc[c] = cand8[(size_t)t * 8 + c];

#pragma unroll
  for (int c = 0; c < 8; ++c) {
    const double* g = Gt + (size_t)myc[c] * DDIM;
    double s = 0.0;
#pragma unroll
    for (int q = 0; q < 8; ++q) {
      const int d = q * 256 + tid;
      s += (double)xs[d] * g[d];
    }
#pragma unroll
    for (int off = 32; off > 0; off >>= 1) s += __shfl_down(s, off);
    if (lane == 0) red[c][w] = s;
  }
  __syncthreads();

  if (tid == 0) {
    double v1 = -1e300, v2 = -1e300;
    int i1 = 0, i2 = 0;
#pragma unroll
    for (int c = 0; c < 8; ++c) {
      const double v = red[c][0] + red[c][1] + red[c][2] + red[c][3] + c64[myc[c]];
      if (v > v1) { v2 = v1; i2 = i1; v1 = v; i1 = myc[c]; }
      else if (v > v2) { v2 = v; i2 = myc[c]; }
    }
    const double e2 = exp(v2 - v1);
    const double s = 1.0 + e2 + 1e-12;
    topk[2 * t] = i1; topk[2 * t + 1] = i2;
    wkf[2 * t] = (float)(1.0 / s);
    wkf[2 * t + 1] = (float)(e2 / s);
  }
}

// ------- deterministic capacity routing: rank in token order, drop >= CAP --
__global__ __launch_bounds__(256) void route_kernel(
    const int* __restrict__ topk, const float* __restrict__ wkf,
    int* __restrict__ slots /* [NEXP][CAP] */, int* __restrict__ counts_eff,
    int* __restrict__ val /* [N] pre-zeroed */)
{
  const int e = blockIdx.x;
  const int tid = threadIdx.x;
  const int lane = tid & 63, wave = tid >> 6;
  __shared__ int wcnt[4];
  __shared__ int sbase;
  if (tid == 0) sbase = 0;
  __syncthreads();

  for (int c0 = 0; c0 < NTOK * 2; c0 += 256) {
    const int a = c0 + tid;
    const bool match = (topk[a] == e) && (wkf[a] > 1e-12f);
    const unsigned long long bal = __ballot(match);
    if (lane == 0) wcnt[wave] = __popcll(bal);
    __syncthreads();
    int base = sbase;
    for (int w = 0; w < 4; ++w)
      if (w < wave) base += wcnt[w];
    const int rank = base + (int)__popcll(bal & ((1ull << lane) - 1ull));
    if (match && rank < CAP) {
      slots[e * CAP + rank] = a;
      val[a] = 1;
    }
    __syncthreads();
    if (tid == 0) sbase += wcnt[0] + wcnt[1] + wcnt[2] + wcnt[3];
  }
  __syncthreads();
  if (tid == 0) counts_eff[e] = (sbase < CAP) ? sbase : CAP;
}

// ----- fused expert: H = silu(U_e @ enc_bf[toks]) in LDS, then Dbuf = w*g*(H@V_e^T)
__global__ __launch_bounds__(256) void expert_fused(
    const unsigned short* __restrict__ encbf, const unsigned short* __restrict__ Ub,
    const unsigned short* __restrict__ Vb, const float* __restrict__ gamma,
    const int* __restrict__ counts_eff, const int* __restrict__ slots,
    const float* __restrict__ wkf, unsigned short* __restrict__ Dbuf)
{
  const int lin = blockIdx.x;                   // 640 wgs
  const int wg = (lin & 7) * 80 + (lin >> 3);   // XCD swizzle: expert locality
  const int e = wg / 10;
  const int t0 = (wg % 10) * 64;
  const int cnt = counts_eff[e];
  if (t0 >= cnt) return;

  __shared__ int aid[64];
  __shared__ int toks[64];
  __shared__ float wts[64];
  __shared__ unsigned short Ht[64 * 128];  // 16 KB (256B-row swizzled)
  __shared__ char U2[32768];               // phase1: At 8KB + Bt(U) 16KB; phase2: Vt 32KB

  const int tid = threadIdx.x;
  const int lane = tid & 63, wid = tid >> 6;
  const int wr = wid >> 1, wc = wid & 1;
  const int fr = lane & 15, fq = lane >> 4;

  if (tid < 64) {
    const int i = t0 + tid;
    if (i < cnt) {
      const int a = slots[e * CAP + i];
      aid[tid] = a;
      toks[tid] = a >> 1;
      wts[tid] = wkf[a] * gamma[e];
    } else {
      aid[tid] = -1;
      toks[tid] = slots[e * CAP] >> 1;
      wts[tid] = 0.f;
    }
  }
  __syncthreads();

  // ---------- phase 1: H = silu(U_e @ enc_bf[toks]^T), BK=64, swizzled ----
  unsigned short* At = (unsigned short*)U2;           // 64 x 64 bf16 (8 KB)
  unsigned short* Bt = (unsigned short*)(U2 + 8192);  // 128 x 64 bf16 (16 KB)
  const unsigned short* Ue = Ub + (size_t)e * RRANK * DDIM;

  size_t aoff[2]; char* adst[2];
#pragma unroll
  for (int is = 0; is < 2; ++is) {
    const int doff = is * 4096 + tid * 16;
    const int r = doff >> 7;
    const int cs = ((doff >> 4) & 7) ^ (r & 7);
    aoff[is] = (size_t)toks[r] * DDIM + cs * 8;
    adst[is] = (char*)At + doff;
  }
  const unsigned short* bsrc[4]; char* bdst[4];
#pragma unroll
  for (int is = 0; is < 4; ++is) {
    const int doff = is * 4096 + tid * 16;
    const int r = doff >> 7;
    const int cs = ((doff >> 4) & 7) ^ (r & 7);
    bsrc[is] = Ue + (size_t)r * DDIM + cs * 8;
    bdst[is] = (char*)Bt + doff;
  }

  f32x4 hacc[2][4];
#pragma unroll
  for (int m = 0; m < 2; ++m)
#pragma unroll
    for (int n = 0; n < 4; ++n) hacc[m][n] = (f32x4){0.f, 0.f, 0.f, 0.f};

  for (int kb = 0; kb < DDIM; kb += 64) {
    __syncthreads();
    gload16(encbf + aoff[0] + kb, adst[0]);
    gload16(encbf + aoff[1] + kb, adst[1]);
#pragma unroll
    for (int is = 0; is < 4; ++is)
      gload16(bsrc[is] + kb, bdst[is]);
    __syncthreads();
#pragma unroll
    for (int kk = 0; kk < 2; ++kk) {
      bf16x8 af[2], bfv[4];
#pragma unroll
      for (int m = 0; m < 2; ++m) {
        const int row = wr * 32 + m * 16 + fr;
        af[m] = *(const bf16x8*)((const char*)At +
                 row * 128 + (((kk * 4 + fq) ^ (row & 7)) << 4));
      }
#pragma unroll
      for (int n = 0; n < 4; ++n) {
        const int row = wc * 64 + n * 16 + fr;
        bfv[n] = *(const bf16x8*)((const char*)Bt +
                  row * 128 + (((kk * 4 + fq) ^ (row & 7)) << 4));
      }
#pragma unroll
      for (int m = 0; m < 2; ++m)
#pragma unroll
        for (int n = 0; n < 4; ++n)
          hacc[m][n] = __builtin_amdgcn_mfma_f32_16x16x32_bf16(af[m], bfv[n], hacc[m][n], 0, 0, 0);
    }
  }

  // write H tile to Ht LDS (swizzled, bf16) with silu
  __syncthreads();
#pragma unroll
  for (int m = 0; m < 2; ++m) {
#pragma unroll
    for (int j = 0; j < 4; ++j) {
      const int row = wr * 32 + m * 16 + fq * 4 + j;
#pragma unroll
      for (int n = 0; n < 4; ++n) {
        const int col = wc * 64 + n * 16 + fr;
        const int b = (row * 256 + col * 2) ^ ((row & 7) << 4);
        *(unsigned short*)((char*)Ht + b) = f2bf(silu_f(hacc[m][n][j]));
      }
    }
  }
  __syncthreads();

  // ---------- phase 2: Dbuf = w*gamma*(H @ V_e^T) --------------------------
  unsigned short* Vt = (unsigned short*)U2;  // 128 x 128 bf16 (32 KB, swizzled)
  const unsigned short* Ve = Vb + (size_t)e * DDIM * RRANK;
  const int hd = tid * 16;

  bf16x8 paf[2][4];
  float wv[2][4];
  int av[2][4];
#pragma unroll
  for (int m = 0; m < 2; ++m) {
    const int row = wr * 32 + m * 16 + fr;
#pragma unroll
    for (int kk = 0; kk < 4; ++kk) {
      const int b = (row * 256 + kk * 64 + fq * 16) ^ ((row & 7) << 4);
      paf[m][kk] = *(const bf16x8*)((const char*)Ht + b);
    }
#pragma unroll
    for (int j = 0; j < 4; ++j) {
      const int tl = wr * 32 + m * 16 + fq * 4 + j;
      wv[m][j] = wts[tl];
      av[m][j] = aid[tl];
    }
  }

  for (int nb = 0; nb < 16; ++nb) {
    __syncthreads();
    const unsigned short* vsrc = Ve + (size_t)nb * 128 * RRANK;
#pragma unroll
    for (int is = 0; is < 8; ++is) {
      const int d = is * 4096 + hd;
      gload16(vsrc + (swz256(d) >> 1), (char*)Vt + d);
    }
    __syncthreads();

    f32x4 acc[2][4];
#pragma unroll
    for (int m = 0; m < 2; ++m)
#pragma unroll
      for (int n = 0; n < 4; ++n) acc[m][n] = (f32x4){0.f, 0.f, 0.f, 0.f};

#pragma unroll
    for (int n = 0; n < 4; ++n) {
      const int drow = wc * 64 + n * 16 + fr;
#pragma unroll
      for (int kk = 0; kk < 4; ++kk) {
        const int b = (drow * 256 + kk * 64 + fq * 16) ^ ((drow & 7) << 4);
        const bf16x8 bfr = *(const bf16x8*)((const char*)Vt + b);
#pragma unroll
        for (int m = 0; m < 2; ++m)
          acc[m][n] = __builtin_amdgcn_mfma_f32_16x16x32_bf16(paf[m][kk], bfr, acc[m][n], 0, 0, 0);
      }
    }

#pragma unroll
    for (int m = 0; m < 2; ++m) {
#pragma unroll
      for (int j = 0; j < 4; ++j) {
        if (av[m][j] >= 0) {
          const float w = wv[m][j];
          unsigned short* dp = Dbuf + (size_t)av[m][j] * DDIM + nb * 128 + wc * 64 + fr;
#pragma unroll
          for (int n = 0; n < 4; ++n)
            dp[n * 16] = f2bf(acc[m][n][j] * w);
        }
      }
    }
  }
}

// -------- combine: y[t] = enc[t] + Dbuf[2t] + Dbuf[2t+1] -------------------
__global__ __launch_bounds__(256) void combine_kernel(
    const unsigned short* __restrict__ Dbuf, const int* __restrict__ val,
    float* __restrict__ y)
{
  const int t = blockIdx.x;
  const int tid = threadIdx.x;
  const int c0 = tid * 8;
  float* yp = y + (size_t)t * DDIM + c0;
  const int v0 = val[2 * t], v1 = val[2 * t + 1];

  float4 o0 = *(const float4*)(yp);
  float4 o1 = *(const float4*)(yp + 4);
  float o[8] = {o0.x, o0.y, o0.z, o0.w, o1.x, o1.y, o1.z, o1.w};

  if (v0) {
    const ushort4 d0 = *(const ushort4*)(Dbuf + (size_t)(2 * t) * DDIM + c0);
    const ushort4 d1 = *(const ushort4*)(Dbuf + (size_t)(2 * t) * DDIM + c0 + 4);
    o[0] += bf2f(d0.x); o[1] += bf2f(d0.y); o[2] += bf2f(d0.z); o[3] += bf2f(d0.w);
    o[4] += bf2f(d1.x); o[5] += bf2f(d1.y); o[6] += bf2f(d1.z); o[7] += bf2f(d1.w);
  }
  if (v1) {
    const ushort4 d0 = *(const ushort4*)(Dbuf + (size_t)(2 * t + 1) * DDIM + c0);
    const ushort4 d1 = *(const ushort4*)(Dbuf + (size_t)(2 * t + 1) * DDIM + c0 + 4);
    o[0] += bf2f(d0.x); o[1] += bf2f(d0.y); o[2] += bf2f(d0.z); o[3] += bf2f(d0.w);
    o[4] += bf2f(d1.x); o[5] += bf2f(d1.y); o[6] += bf2f(d1.z); o[7] += bf2f(d1.w);
  }
  *(float4*)(yp) = (float4){o[0], o[1], o[2], o[3]};
  *(float4*)(yp + 4) = (float4){o[4], o[5], o[6], o[7]};
}

extern "C" void kernel_launch(void* const* d_in, const int* in_sizes, int n_in,
                              void* d_out, int out_size, void* d_ws, size_t ws_size,
                              hipStream_t stream)
{
  const float* x     = (const float*)d_in[0];
  const float* We    = (const float*)d_in[1];
  const float* be    = (const float*)d_in[2];
  const float* Wg    = (const float*)d_in[3];
  const float* U     = (const float*)d_in[4];
  const float* V     = (const float*)d_in[5];
  const float* gamma = (const float*)d_in[6];
  float* y = (float*)d_out;

  char* ws = (char*)d_ws;
  // small persistent buffers
  int*            topk       = (int*)(ws + 0);                   // 128 KB
  float*          wkf        = (float*)(ws + 131072);            // 128 KB
  int*            counts_eff = (int*)(ws + 262144);              // 256 B
  double*         c64        = (double*)(ws + 262400);           // 512 B
  int*            cand8      = (int*)(ws + 262912);              // 512 KB
  double*         Gt         = (double*)(ws + 787200);           // 1 MB
  unsigned short* G_bf       = (unsigned short*)(ws + 1835776);  // 256 KB
  int*            slots      = (int*)(ws + 2097920);             // 160 KB
  int*            val        = (int*)(ws + 2261760);             // 128 KB
  // Dbuf region (128 MB) ALIASES {x_bf, We_bf, Gpart}: those are dead before
  // expert_fused writes Dbuf (stream-ordered), combine reads Dbuf after.
  unsigned short* Dbuf       = (unsigned short*)(ws + 2392832);  // 128 MB
  unsigned short* x_bf       = (unsigned short*)(ws + 2392832);  // 64 MB (alias)
  unsigned short* We_bf      = (unsigned short*)(ws + 69501696); // 8 MB (alias)
  double*         Gpart      = (double*)(ws + 77890304);         // 8 MB (alias)
  // long-lived bf16 weights + enc
  unsigned short* U_bf       = (unsigned short*)(ws + 136610560);// 32 MB
  unsigned short* V_bf       = (unsigned short*)(ws + 170164992);// 32 MB
  unsigned short* enc_bf     = (unsigned short*)(ws + 203719424);// 64 MB
  // total ws use ~258.3 MB

  hipMemsetAsync(val, 0, 131072, stream);

  cvt_all_kernel<<<dim3(2048), 256, 0, stream>>>(x, We, U, V, x_bf, We_bf, U_bf, V_bf);

  gmat_part_kernel<<<dim3(32, 8), 256, 0, stream>>>(We, Wg, Gpart);
  greduce_kernel<<<dim3(512), 256, 0, stream>>>(Gpart, Gt, G_bf);
  bias_c_kernel<<<dim3(64), 256, 0, stream>>>(be, Wg, c64);
  logits_topc_kernel<<<dim3(128), 256, 0, stream>>>(x_bf, G_bf, c64, cand8);
  refine_kernel<<<dim3(NTOK), 256, 0, stream>>>(x, Gt, c64, cand8, topk, wkf);
  route_kernel<<<dim3(64), 256, 0, stream>>>(topk, wkf, slots, counts_eff, val);

  enc_mfma3<<<dim3(2048), 256, 0, stream>>>(x_bf, We_bf, be, y, enc_bf);
  expert_fused<<<dim3(640), 256, 0, stream>>>(enc_bf, U_bf, V_bf, gamma, counts_eff, slots, wkf, Dbuf);
  combine_kernel<<<dim3(NTOK), 256, 0, stream>>>(Dbuf, val, y);
}

// Round 8
// 742.310 us; speedup vs baseline: 4.5484x; 1.0729x over previous
//
#include <hip/hip_runtime.h>
#include <math.h>

#define NTOK 16384
#define DDIM 2048
#define NEXP 64
#define RRANK 128
#define CAP 640  // ceil(1.25 * 32768 / 64)

typedef __attribute__((ext_vector_type(8))) short bf16x8;
typedef __attribute__((ext_vector_type(4))) float f32x4;
typedef __attribute__((address_space(1))) const unsigned int gu32_t;
typedef __attribute__((address_space(3))) unsigned int lu32_t;

__device__ __forceinline__ void gload16(const void* g, void* l) {
  __builtin_amdgcn_global_load_lds((gu32_t*)g, (lu32_t*)l, 16, 0, 0);
}

__device__ __forceinline__ float silu_f(float v) {
  return v / (1.f + expf(-v));
}

__device__ __forceinline__ unsigned short f2bf(float f) {
  unsigned int u = __float_as_uint(f);
  unsigned int r = (u + 0x7fffu + ((u >> 16) & 1u)) >> 16;
  return (unsigned short)r;
}

__device__ __forceinline__ float bf2f(unsigned short u) {
  return __uint_as_float(((unsigned int)u) << 16);
}

__device__ __forceinline__ int swz256(int d) {  // XOR-swizzle for 256B-row tiles
  return d ^ (((d >> 8) & 7) << 4);
}

// ---------------- fp32 -> bf16 bulk convert (all 4 tensors, 1 launch) ------
__global__ __launch_bounds__(256) void cvt_all_kernel(
    const float* __restrict__ x, const float* __restrict__ We,
    const float* __restrict__ U, const float* __restrict__ V,
    unsigned short* __restrict__ xb, unsigned short* __restrict__ Web,
    unsigned short* __restrict__ Ub, unsigned short* __restrict__ Vb)
{
  const int S0 = NTOK * DDIM / 4;
  const int S1 = DDIM * DDIM / 4;
  const int S2 = NEXP * RRANK * DDIM / 4;
  const int total = S0 + S1 + 2 * S2;
  int i = blockIdx.x * 256 + threadIdx.x;
  const int stride = gridDim.x * 256;
  for (; i < total; i += stride) {
    const float* in; unsigned short* out; int j;
    if (i < S0) { in = x; out = xb; j = i; }
    else if (i < S0 + S1) { in = We; out = Web; j = i - S0; }
    else if (i < S0 + S1 + S2) { in = U; out = Ub; j = i - S0 - S1; }
    else { in = V; out = Vb; j = i - S0 - S1 - S2; }
    const float4 v = ((const float4*)in)[j];
    ushort4 o;
    o.x = f2bf(v.x); o.y = f2bf(v.y); o.z = f2bf(v.z); o.w = f2bf(v.w);
    ((ushort4*)out)[j] = o;
  }
}

// ---------------- encoder GEMM (bf16 MFMA, BK=64, swizzled, bf16-out only) -
// Identical to round-6 enc_mfma3 EXCEPT the fp32 y write is removed.
__global__ __launch_bounds__(256) void enc_mfma4(
    const unsigned short* __restrict__ xb, const unsigned short* __restrict__ Web,
    const float* __restrict__ be, unsigned short* __restrict__ encbf)
{
  __shared__ unsigned short At[128 * 64];  // 16 KB (chunk-swizzled)
  __shared__ unsigned short Bt[128 * 64];  // 16 KB
  const int tid = threadIdx.x;
  const int lane = tid & 63, wid = tid >> 6;
  const int wr = wid >> 1, wc = wid & 1;
  const int fr = lane & 15, fq = lane >> 4;
  const int bid = blockIdx.x;
  const int wg = (bid & 7) * 256 + (bid >> 3);  // bijective XCD swizzle
  const int n0 = (wg & 15) * 128, m0 = (wg >> 4) * 128;

  // staging: 4 issues x 256thr x 16B per tile; linear LDS dest, swizzled src
  const unsigned short* asrc[4];
  const unsigned short* bsrc[4];
  char* adst[4];
  char* bdst[4];
#pragma unroll
  for (int is = 0; is < 4; ++is) {
    const int doff = is * 4096 + tid * 16;
    const int r = doff >> 7;                 // 128B rows
    const int cs = ((doff >> 4) & 7) ^ (r & 7);
    asrc[is] = xb + (size_t)(m0 + r) * DDIM + cs * 8;
    bsrc[is] = Web + (size_t)(n0 + r) * DDIM + cs * 8;
    adst[is] = (char*)At + doff;
    bdst[is] = (char*)Bt + doff;
  }

  f32x4 acc[4][4];
#pragma unroll
  for (int m = 0; m < 4; ++m)
#pragma unroll
    for (int n = 0; n < 4; ++n) acc[m][n] = (f32x4){0.f, 0.f, 0.f, 0.f};

  for (int kb = 0; kb < DDIM; kb += 64) {
    __syncthreads();
#pragma unroll
    for (int is = 0; is < 4; ++is) {
      gload16(asrc[is] + kb, adst[is]);
      gload16(bsrc[is] + kb, bdst[is]);
    }
    __syncthreads();
#pragma unroll
    for (int kk = 0; kk < 2; ++kk) {
      bf16x8 af[4], bfv[4];
#pragma unroll
      for (int m = 0; m < 4; ++m) {
        const int row = wr * 64 + m * 16 + fr;
        af[m] = *(const bf16x8*)((const char*)At +
                 row * 128 + (((kk * 4 + fq) ^ (row & 7)) << 4));
      }
#pragma unroll
      for (int n = 0; n < 4; ++n) {
        const int row = wc * 64 + n * 16 + fr;
        bfv[n] = *(const bf16x8*)((const char*)Bt +
                  row * 128 + (((kk * 4 + fq) ^ (row & 7)) << 4));
      }
#pragma unroll
      for (int m = 0; m < 4; ++m)
#pragma unroll
        for (int n = 0; n < 4; ++n)
          acc[m][n] = __builtin_amdgcn_mfma_f32_16x16x32_bf16(af[m], bfv[n], acc[m][n], 0, 0, 0);
    }
  }

  float bias[4];
#pragma unroll
  for (int n = 0; n < 4; ++n) bias[n] = be[n0 + wc * 64 + n * 16 + fr];
#pragma unroll
  for (int m = 0; m < 4; ++m) {
#pragma unroll
    for (int j = 0; j < 4; ++j) {
      const int row = m0 + wr * 64 + m * 16 + fq * 4 + j;
      unsigned short* ob = encbf + (size_t)row * DDIM + n0 + wc * 64 + fr;
#pragma unroll
      for (int n = 0; n < 4; ++n)
        ob[n * 16] = f2bf(acc[m][n][j] + bias[n]);
    }
  }
}

// ------- G partials (fp64): Gpart[oc][e][d] over o-chunk oc ----------------
__global__ __launch_bounds__(256) void gmat_part_kernel(
    const float* __restrict__ We, const float* __restrict__ Wg,
    double* __restrict__ Gpart)
{
  __shared__ float As[64][68];  // [o][d]
  __shared__ float Bs[64][68];  // [o][e]
  const int tid = threadIdx.x;
  const int d0 = blockIdx.x * 64;
  const int oc = blockIdx.y;
  const int tx = tid & 15, ty = tid >> 4;
  const int row = tid >> 2, p = (tid & 3) * 16;

  double acc[4][4];
#pragma unroll
  for (int j = 0; j < 4; ++j)
#pragma unroll
    for (int i = 0; i < 4; ++i) acc[j][i] = 0.0;

  for (int o0 = oc * 256; o0 < oc * 256 + 256; o0 += 64) {
    float4 wv[4], gv[4];
#pragma unroll
    for (int q = 0; q < 4; ++q) {
      wv[q] = *(const float4*)(We + (size_t)(o0 + row) * DDIM + d0 + p + q * 4);
      gv[q] = *(const float4*)(Wg + (size_t)row * DDIM + o0 + p + q * 4);
    }
    __syncthreads();
#pragma unroll
    for (int q = 0; q < 4; ++q) {
      const int c = p + q * 4;
      As[row][c + 0] = wv[q].x; As[row][c + 1] = wv[q].y;
      As[row][c + 2] = wv[q].z; As[row][c + 3] = wv[q].w;
      Bs[c + 0][row] = gv[q].x; Bs[c + 1][row] = gv[q].y;
      Bs[c + 2][row] = gv[q].z; Bs[c + 3][row] = gv[q].w;
    }
    __syncthreads();
#pragma unroll 8
    for (int oo = 0; oo < 64; ++oo) {
      double a[4], b[4];
#pragma unroll
      for (int j = 0; j < 4; ++j) a[j] = (double)As[oo][ty * 4 + j];
#pragma unroll
      for (int i = 0; i < 4; ++i) b[i] = (double)Bs[oo][tx * 4 + i];
#pragma unroll
      for (int j = 0; j < 4; ++j)
#pragma unroll
        for (int i = 0; i < 4; ++i)
          acc[j][i] = fma(a[j], b[i], acc[j][i]);
    }
    __syncthreads();
  }
#pragma unroll
  for (int j = 0; j < 4; ++j)
#pragma unroll
    for (int i = 0; i < 4; ++i) {
      const int d = d0 + ty * 4 + j, e = tx * 4 + i;
      Gpart[(size_t)oc * (DDIM * NEXP) + (size_t)e * DDIM + d] = acc[j][i];
    }
}

// ------- reduce partials -> Gt (fp64) + G_bf (bf16) ------------------------
__global__ __launch_bounds__(256) void greduce_kernel(
    const double* __restrict__ Gpart, double* __restrict__ Gt,
    unsigned short* __restrict__ Gbf)
{
  const int idx = blockIdx.x * 256 + threadIdx.x;  // 131072 total
  double s = 0.0;
#pragma unroll
  for (int oc = 0; oc < 8; ++oc)
    s += Gpart[(size_t)oc * (DDIM * NEXP) + idx];
  Gt[idx] = s;
  Gbf[idx] = f2bf((float)s);
}

// ---------------- c[e] = be . Wg[e]  (fp64) --------------------------------
__global__ __launch_bounds__(256) void bias_c_kernel(
    const float* __restrict__ be, const float* __restrict__ Wg,
    double* __restrict__ c64)
{
  const int e = blockIdx.x;
  const int tid = threadIdx.x;
  double s = 0.0;
  for (int o = tid; o < DDIM; o += 256)
    s += (double)be[o] * (double)Wg[(size_t)e * DDIM + o];
  __shared__ double red[256];
  red[tid] = s;
  __syncthreads();
  for (int st = 128; st > 0; st >>= 1) {
    if (tid < st) red[tid] += red[tid + st];
    __syncthreads();
  }
  if (tid == 0) c64[e] = red[0];
}

// ---- approx logits (bf16 MFMA) + fused per-token top-8 candidates ---------
// (round-6 version, 128 tokens/block, grid 128 — known good)
__global__ __launch_bounds__(256) void logits_topc_kernel(
    const unsigned short* __restrict__ xb, const unsigned short* __restrict__ Gbf,
    const double* __restrict__ c64, int* __restrict__ cand8)
{
  __shared__ unsigned short At[128 * 32];  // 8 KB: tokens x k
  __shared__ unsigned short Bt[64 * 32];   // 4 KB: experts x k
  __shared__ float Ls[128][64];            // 32 KB logits
  const int tid = threadIdx.x;
  const int lane = tid & 63, wid = tid >> 6;
  const int fr = lane & 15, fq = lane >> 4;
  const int t0 = blockIdx.x * 128;

  const int doff0 = wid * 1024 + lane * 16;  // == tid*16
  const int doff1 = doff0 + 4096;
  const unsigned short* as0 = xb + (size_t)(t0 + (doff0 >> 6)) * DDIM + ((doff0 & 63) >> 1);
  const unsigned short* as1 = xb + (size_t)(t0 + (doff1 >> 6)) * DDIM + ((doff1 & 63) >> 1);
  const unsigned short* bs0 = Gbf + (size_t)(doff0 >> 6) * DDIM + ((doff0 & 63) >> 1);
  char* ad0 = (char*)At + doff0; char* ad1 = (char*)At + doff1;
  char* bd0 = (char*)Bt + doff0;

  f32x4 acc[2][4];
#pragma unroll
  for (int m = 0; m < 2; ++m)
#pragma unroll
    for (int n = 0; n < 4; ++n) acc[m][n] = (f32x4){0.f, 0.f, 0.f, 0.f};

  for (int kb = 0; kb < DDIM; kb += 32) {
    __syncthreads();
    gload16(as0 + kb, ad0);
    gload16(as1 + kb, ad1);
    gload16(bs0 + kb, bd0);
    __syncthreads();
    bf16x8 af[2], bfr[4];
#pragma unroll
    for (int m = 0; m < 2; ++m)
      af[m] = *(const bf16x8*)&At[(wid * 32 + m * 16 + fr) * 32 + fq * 8];
#pragma unroll
    for (int n = 0; n < 4; ++n)
      bfr[n] = *(const bf16x8*)&Bt[(n * 16 + fr) * 32 + fq * 8];
#pragma unroll
    for (int m = 0; m < 2; ++m)
#pragma unroll
      for (int n = 0; n < 4; ++n)
        acc[m][n] = __builtin_amdgcn_mfma_f32_16x16x32_bf16(af[m], bfr[n], acc[m][n], 0, 0, 0);
  }

#pragma unroll
  for (int m = 0; m < 2; ++m)
#pragma unroll
    for (int j = 0; j < 4; ++j) {
      const int row = wid * 32 + m * 16 + fq * 4 + j;
#pragma unroll
      for (int n = 0; n < 4; ++n)
        Ls[row][n * 16 + fr] = acc[m][n][j];
    }
  __syncthreads();

  if (tid < 128) {
    float v8[8];
    int i8[8];
#pragma unroll
    for (int c = 0; c < 8; ++c) { v8[c] = -INFINITY; i8[c] = 0; }
    for (int e = 0; e < NEXP; ++e) {
      const float v = Ls[tid][e] + (float)c64[e];
      if (v > v8[7]) {
        int p = 7;
        while (p > 0 && v > v8[p - 1]) { v8[p] = v8[p - 1]; i8[p] = i8[p - 1]; --p; }
        v8[p] = v; i8[p] = e;
      }
    }
    int* cp = cand8 + (size_t)(t0 + tid) * 8;
#pragma unroll
    for (int c = 0; c < 8; ++c) cp[c] = i8[c];
  }
}

// ---- exact fp64 refine of 8 candidates: top-2 + softmax -------------------
__global__ __launch_bounds__(256) void refine_kernel(
    const float* __restrict__ x, const double* __restrict__ Gt,
    const double* __restrict__ c64, const int* __restrict__ cand8,
    int* __restrict__ topk, float* __restrict__ wkf)
{
  const int t = blockIdx.x;
  const int tid = threadIdx.x;
  const int lane = tid & 63, w = tid >> 6;
  __shared__ float xs[DDIM];
  __shared__ double red[8][4];

  ((float4*)xs)[tid] = ((const float4*)(x + (size_t)t * DDIM))[tid];
  ((float4*)xs)[tid + 256] = ((const float4*)(x + (size_t)t * DDIM))[tid + 256];
  __syncthreads();

  int myc[8];
#pragma unroll
  for (int c = 0; c < 8; ++c) myc[c] = cand8[(size_t)t * 8 + c];

#pragma unroll
  for (int c = 0; c < 8; ++c) {
    const double* g = Gt + (size_t)myc[c] * DDIM;
    double s = 0.0;
#pragma unroll
    for (int q = 0; q < 8; ++q) {
      const int d = q * 256 + tid;
      s += (double)xs[d] * g[d];
    }
#pragma unroll
    for (int off = 32; off > 0; off >>= 1) s += __shfl_down(s, off);
    if (lane == 0) red[c][w] = s;
  }
  __syncthreads();

  if (tid == 0) {
    double v1 = -1e300, v2 = -1e300;
    int i1 = 0, i2 = 0;
#pragma unroll
    for (int c = 0; c < 8; ++c) {
      const double v = red[c][0] + red[c][1] + red[c][2] + red[c][3] + c64[myc[c]];
      if (v > v1) { v2 = v1; i2 = i1; v1 = v; i1 = myc[c]; }
      else if (v > v2) { v2 = v; i2 = myc[c]; }
    }
    const double e2 = exp(v2 - v1);
    const double s = 1.0 + e2 + 1e-12;
    topk[2 * t] = i1; topk[2 * t + 1] = i2;
    wkf[2 * t] = (float)(1.0 / s);
    wkf[2 * t + 1] = (float)(e2 / s);
  }
}

// ------- deterministic capacity routing: rank in token order, drop >= CAP --
__global__ __launch_bounds__(256) void route_kernel(
    const int* __restrict__ topk, const float* __restrict__ wkf,
    int* __restrict__ slots /* [NEXP][CAP] */, int* __restrict__ counts_eff,
    int* __restrict__ val /* [N] pre-zeroed */)
{
  const int e = blockIdx.x;
  const int tid = threadIdx.x;
  const int lane = tid & 63, wave = tid >> 6;
  __shared__ int wcnt[4];
  __shared__ int sbase;
  if (tid == 0) sbase = 0;
  __syncthreads();

  for (int c0 = 0; c0 < NTOK * 2; c0 += 256) {
    const int a = c0 + tid;
    const bool match = (topk[a] == e) && (wkf[a] > 1e-12f);
    const unsigned long long bal = __ballot(match);
    if (lane == 0) wcnt[wave] = __popcll(bal);
    __syncthreads();
    int base = sbase;
    for (int w = 0; w < 4; ++w)
      if (w < wave) base += wcnt[w];
    const int rank = base + (int)__popcll(bal & ((1ull << lane) - 1ull));
    if (match && rank < CAP) {
      slots[e * CAP + rank] = a;
      val[a] = 1;
    }
    __syncthreads();
    if (tid == 0) sbase += wcnt[0] + wcnt[1] + wcnt[2] + wcnt[3];
  }
  __syncthreads();
  if (tid == 0) counts_eff[e] = (sbase < CAP) ? sbase : CAP;
}

// ----- fused expert: H = silu(U_e @ enc_bf[toks]) in LDS, then Dbuf = w*g*(H@V_e^T)
__global__ __launch_bounds__(256) void expert_fused(
    const unsigned short* __restrict__ encbf, const unsigned short* __restrict__ Ub,
    const unsigned short* __restrict__ Vb, const float* __restrict__ gamma,
    const int* __restrict__ counts_eff, const int* __restrict__ slots,
    const float* __restrict__ wkf, unsigned short* __restrict__ Dbuf)
{
  const int lin = blockIdx.x;                   // 640 wgs
  const int wg = (lin & 7) * 80 + (lin >> 3);   // XCD swizzle: expert locality
  const int e = wg / 10;
  const int t0 = (wg % 10) * 64;
  const int cnt = counts_eff[e];
  if (t0 >= cnt) return;

  __shared__ int aid[64];
  __shared__ int toks[64];
  __shared__ float wts[64];
  __shared__ unsigned short Ht[64 * 128];  // 16 KB (256B-row swizzled)
  __shared__ char U2[32768];               // phase1: At 8KB + Bt(U) 16KB; phase2: Vt 32KB

  const int tid = threadIdx.x;
  const int lane = tid & 63, wid = tid >> 6;
  const int wr = wid >> 1, wc = wid & 1;
  const int fr = lane & 15, fq = lane >> 4;

  if (tid < 64) {
    const int i = t0 + tid;
    if (i < cnt) {
      const int a = slots[e * CAP + i];
      aid[tid] = a;
      toks[tid] = a >> 1;
      wts[tid] = wkf[a] * gamma[e];
    } else {
      aid[tid] = -1;
      toks[tid] = slots[e * CAP] >> 1;
      wts[tid] = 0.f;
    }
  }
  __syncthreads();

  // ---------- phase 1: H = silu(U_e @ enc_bf[toks]^T), BK=64, swizzled ----
  unsigned short* At = (unsigned short*)U2;           // 64 x 64 bf16 (8 KB)
  unsigned short* Bt = (unsigned short*)(U2 + 8192);  // 128 x 64 bf16 (16 KB)
  const unsigned short* Ue = Ub + (size_t)e * RRANK * DDIM;

  size_t aoff[2]; char* adst[2];
#pragma unroll
  for (int is = 0; is < 2; ++is) {
    const int doff = is * 4096 + tid * 16;
    const int r = doff >> 7;
    const int cs = ((doff >> 4) & 7) ^ (r & 7);
    aoff[is] = (size_t)toks[r] * DDIM + cs * 8;
    adst[is] = (char*)At + doff;
  }
  const unsigned short* bsrc[4]; char* bdst[4];
#pragma unroll
  for (int is = 0; is < 4; ++is) {
    const int doff = is * 4096 + tid * 16;
    const int r = doff >> 7;
    const int cs = ((doff >> 4) & 7) ^ (r & 7);
    bsrc[is] = Ue + (size_t)r * DDIM + cs * 8;
    bdst[is] = (char*)Bt + doff;
  }

  f32x4 hacc[2][4];
#pragma unroll
  for (int m = 0; m < 2; ++m)
#pragma unroll
    for (int n = 0; n < 4; ++n) hacc[m][n] = (f32x4){0.f, 0.f, 0.f, 0.f};

  for (int kb = 0; kb < DDIM; kb += 64) {
    __syncthreads();
    gload16(encbf + aoff[0] + kb, adst[0]);
    gload16(encbf + aoff[1] + kb, adst[1]);
#pragma unroll
    for (int is = 0; is < 4; ++is)
      gload16(bsrc[is] + kb, bdst[is]);
    __syncthreads();
#pragma unroll
    for (int kk = 0; kk < 2; ++kk) {
      bf16x8 af[2], bfv[4];
#pragma unroll
      for (int m = 0; m < 2; ++m) {
        const int row = wr * 32 + m * 16 + fr;
        af[m] = *(const bf16x8*)((const char*)At +
                 row * 128 + (((kk * 4 + fq) ^ (row & 7)) << 4));
      }
#pragma unroll
      for (int n = 0; n < 4; ++n) {
        const int row = wc * 64 + n * 16 + fr;
        bfv[n] = *(const bf16x8*)((const char*)Bt +
                  row * 128 + (((kk * 4 + fq) ^ (row & 7)) << 4));
      }
#pragma unroll
      for (int m = 0; m < 2; ++m)
#pragma unroll
        for (int n = 0; n < 4; ++n)
          hacc[m][n] = __builtin_amdgcn_mfma_f32_16x16x32_bf16(af[m], bfv[n], hacc[m][n], 0, 0, 0);
    }
  }

  // write H tile to Ht LDS (swizzled, bf16) with silu
  __syncthreads();
#pragma unroll
  for (int m = 0; m < 2; ++m) {
#pragma unroll
    for (int j = 0; j < 4; ++j) {
      const int row = wr * 32 + m * 16 + fq * 4 + j;
#pragma unroll
      for (int n = 0; n < 4; ++n) {
        const int col = wc * 64 + n * 16 + fr;
        const int b = (row * 256 + col * 2) ^ ((row & 7) << 4);
        *(unsigned short*)((char*)Ht + b) = f2bf(silu_f(hacc[m][n][j]));
      }
    }
  }
  __syncthreads();

  // ---------- phase 2: Dbuf = w*gamma*(H @ V_e^T) --------------------------
  unsigned short* Vt = (unsigned short*)U2;  // 128 x 128 bf16 (32 KB, swizzled)
  const unsigned short* Ve = Vb + (size_t)e * DDIM * RRANK;
  const int hd = tid * 16;

  bf16x8 paf[2][4];
  float wv[2][4];
  int av[2][4];
#pragma unroll
  for (int m = 0; m < 2; ++m) {
    const int row = wr * 32 + m * 16 + fr;
#pragma unroll
    for (int kk = 0; kk < 4; ++kk) {
      const int b = (row * 256 + kk * 64 + fq * 16) ^ ((row & 7) << 4);
      paf[m][kk] = *(const bf16x8*)((const char*)Ht + b);
    }
#pragma unroll
    for (int j = 0; j < 4; ++j) {
      const int tl = wr * 32 + m * 16 + fq * 4 + j;
      wv[m][j] = wts[tl];
      av[m][j] = aid[tl];
    }
  }

  for (int nb = 0; nb < 16; ++nb) {
    __syncthreads();
    const unsigned short* vsrc = Ve + (size_t)nb * 128 * RRANK;
#pragma unroll
    for (int is = 0; is < 8; ++is) {
      const int d = is * 4096 + hd;
      gload16(vsrc + (swz256(d) >> 1), (char*)Vt + d);
    }
    __syncthreads();

    f32x4 acc[2][4];
#pragma unroll
    for (int m = 0; m < 2; ++m)
#pragma unroll
      for (int n = 0; n < 4; ++n) acc[m][n] = (f32x4){0.f, 0.f, 0.f, 0.f};

#pragma unroll
    for (int n = 0; n < 4; ++n) {
      const int drow = wc * 64 + n * 16 + fr;
#pragma unroll
      for (int kk = 0; kk < 4; ++kk) {
        const int b = (drow * 256 + kk * 64 + fq * 16) ^ ((drow & 7) << 4);
        const bf16x8 bfr = *(const bf16x8*)((const char*)Vt + b);
#pragma unroll
        for (int m = 0; m < 2; ++m)
          acc[m][n] = __builtin_amdgcn_mfma_f32_16x16x32_bf16(paf[m][kk], bfr, acc[m][n], 0, 0, 0);
      }
    }

#pragma unroll
    for (int m = 0; m < 2; ++m) {
#pragma unroll
      for (int j = 0; j < 4; ++j) {
        if (av[m][j] >= 0) {
          const float w = wv[m][j];
          unsigned short* dp = Dbuf + (size_t)av[m][j] * DDIM + nb * 128 + wc * 64 + fr;
#pragma unroll
          for (int n = 0; n < 4; ++n)
            dp[n * 16] = f2bf(acc[m][n][j] * w);
        }
      }
    }
  }
}

// -------- combine: y[t] = enc_bf[t] + Dbuf[2t] + Dbuf[2t+1] ----------------
__global__ __launch_bounds__(256) void combine_kernel(
    const unsigned short* __restrict__ encbf, const unsigned short* __restrict__ Dbuf,
    const int* __restrict__ val, float* __restrict__ y)
{
  const int t = blockIdx.x;
  const int tid = threadIdx.x;
  const int c0 = tid * 8;
  float* yp = y + (size_t)t * DDIM + c0;
  const int v0 = val[2 * t], v1 = val[2 * t + 1];

  const ushort4 e0 = *(const ushort4*)(encbf + (size_t)t * DDIM + c0);
  const ushort4 e1 = *(const ushort4*)(encbf + (size_t)t * DDIM + c0 + 4);
  float o[8] = {bf2f(e0.x), bf2f(e0.y), bf2f(e0.z), bf2f(e0.w),
                bf2f(e1.x), bf2f(e1.y), bf2f(e1.z), bf2f(e1.w)};

  if (v0) {
    const ushort4 d0 = *(const ushort4*)(Dbuf + (size_t)(2 * t) * DDIM + c0);
    const ushort4 d1 = *(const ushort4*)(Dbuf + (size_t)(2 * t) * DDIM + c0 + 4);
    o[0] += bf2f(d0.x); o[1] += bf2f(d0.y); o[2] += bf2f(d0.z); o[3] += bf2f(d0.w);
    o[4] += bf2f(d1.x); o[5] += bf2f(d1.y); o[6] += bf2f(d1.z); o[7] += bf2f(d1.w);
  }
  if (v1) {
    const ushort4 d0 = *(const ushort4*)(Dbuf + (size_t)(2 * t + 1) * DDIM + c0);
    const ushort4 d1 = *(const ushort4*)(Dbuf + (size_t)(2 * t + 1) * DDIM + c0 + 4);
    o[0] += bf2f(d0.x); o[1] += bf2f(d0.y); o[2] += bf2f(d0.z); o[3] += bf2f(d0.w);
    o[4] += bf2f(d1.x); o[5] += bf2f(d1.y); o[6] += bf2f(d1.z); o[7] += bf2f(d1.w);
  }
  *(float4*)(yp) = (float4){o[0], o[1], o[2], o[3]};
  *(float4*)(yp + 4) = (float4){o[4], o[5], o[6], o[7]};
}

extern "C" void kernel_launch(void* const* d_in, const int* in_sizes, int n_in,
                              void* d_out, int out_size, void* d_ws, size_t ws_size,
                              hipStream_t stream)
{
  const float* x     = (const float*)d_in[0];
  const float* We    = (const float*)d_in[1];
  const float* be    = (const float*)d_in[2];
  const float* Wg    = (const float*)d_in[3];
  const float* U     = (const float*)d_in[4];
  const float* V     = (const float*)d_in[5];
  const float* gamma = (const float*)d_in[6];
  float* y = (float*)d_out;

  char* ws = (char*)d_ws;
  // small persistent buffers
  int*            topk       = (int*)(ws + 0);                   // 128 KB
  float*          wkf        = (float*)(ws + 131072);            // 128 KB
  int*            counts_eff = (int*)(ws + 262144);              // 256 B
  double*         c64        = (double*)(ws + 262400);           // 512 B
  int*            cand8      = (int*)(ws + 262912);              // 512 KB
  double*         Gt         = (double*)(ws + 787200);           // 1 MB
  unsigned short* G_bf       = (unsigned short*)(ws + 1835776);  // 256 KB
  int*            slots      = (int*)(ws + 2097920);             // 160 KB
  int*            val        = (int*)(ws + 2261760);             // 128 KB
  // Dbuf region (128 MB) ALIASES {x_bf, We_bf, Gpart}: those are dead before
  // expert_fused writes Dbuf (stream-ordered), combine reads Dbuf after.
  unsigned short* Dbuf       = (unsigned short*)(ws + 2392832);  // 128 MB
  unsigned short* x_bf       = (unsigned short*)(ws + 2392832);  // 64 MB (alias)
  unsigned short* We_bf      = (unsigned short*)(ws + 69501696); // 8 MB (alias)
  double*         Gpart      = (double*)(ws + 77890304);         // 8 MB (alias)
  // long-lived bf16 weights + enc
  unsigned short* U_bf       = (unsigned short*)(ws + 136610560);// 32 MB
  unsigned short* V_bf       = (unsigned short*)(ws + 170164992);// 32 MB
  unsigned short* enc_bf     = (unsigned short*)(ws + 203719424);// 64 MB
  // total ws use ~258.3 MB

  hipMemsetAsync(val, 0, 131072, stream);

  cvt_all_kernel<<<dim3(2048), 256, 0, stream>>>(x, We, U, V, x_bf, We_bf, U_bf, V_bf);

  gmat_part_kernel<<<dim3(32, 8), 256, 0, stream>>>(We, Wg, Gpart);
  greduce_kernel<<<dim3(512), 256, 0, stream>>>(Gpart, Gt, G_bf);
  bias_c_kernel<<<dim3(64), 256, 0, stream>>>(be, Wg, c64);
  logits_topc_kernel<<<dim3(128), 256, 0, stream>>>(x_bf, G_bf, c64, cand8);
  refine_kernel<<<dim3(NTOK), 256, 0, stream>>>(x, Gt, c64, cand8, topk, wkf);
  route_kernel<<<dim3(64), 256, 0, stream>>>(topk, wkf, slots, counts_eff, val);

  enc_mfma4<<<dim3(2048), 256, 0, stream>>>(x_bf, We_bf, be, enc_bf);
  expert_fused<<<dim3(640), 256, 0, stream>>>(enc_bf, U_bf, V_bf, gamma, counts_eff, slots, wkf, Dbuf);
  combine_kernel<<<dim3(NTOK), 256, 0, stream>>>(enc_bf, Dbuf, val, y);
}